// Round 6
// baseline (2059.445 us; speedup 1.0000x reference)
//
#include <hip/hip_runtime.h>

#define N_USERS 50000
#define N_ENT   150000
#define N_NODES 200000
#define NE      2000000
#define BATCH   8192

// bucket sort params: 128 rows per bucket (bucket tile lives in LDS)
#define BSHIFT 7
#define BROWS  128
#define NBUK   1563           // ceil(200000 / 128)
#define EPB    8192           // edges per block in hist/partition
#define PBLK   245            // ceil(NE / EPB)
#define T0_BLKS 12500         // N_NODES*64/4 / 256
#define WT_BLKS 52            // ceil(13312 / 256)

typedef __attribute__((ext_vector_type(8))) short   bf16x8;
typedef __attribute__((ext_vector_type(4))) float   f32x4;
typedef unsigned int u32;

__device__ __forceinline__ float bf2f(unsigned short b) {
    return __uint_as_float(((u32)b) << 16);
}
__device__ __forceinline__ float bflo(u32 x) {          // low bf16 of a pair
    return __uint_as_float(x << 16);
}
__device__ __forceinline__ float bfhi(u32 x) {          // high bf16 of a pair
    return __uint_as_float(x & 0xFFFF0000u);
}
__device__ __forceinline__ unsigned short f2bf(float f) {
    u32 u = __float_as_uint(f);
    u += 0x7FFF + ((u >> 16) & 1);          // round-to-nearest-even
    return (unsigned short)(u >> 16);
}
// pack 2 f32 -> 1 u32 of 2 bf16 (RNE), single instruction on gfx950
__device__ __forceinline__ u32 cvtpk(float lo, float hi) {
    u32 r;
    asm("v_cvt_pk_bf16_f32 %0, %1, %2" : "=v"(r) : "v"(lo), "v"(hi));
    return r;
}

// ===========================================================================
// Bucket build (bfill ELIMINATED — layer kernels consume `part` directly and
// accumulate per-row in LDS, so within-bucket row sort is unnecessary):
//   bhist: LDS histogram of bucket (row>>7) counts       (int4 streamed)
//   bscan: exclusive scan of 1563 bucket counts (2-chunk butterfly)
//   part_kernel: partition edges bucket-contiguous, records {(lrow<<18)|col, val}
// ===========================================================================
__global__ __launch_bounds__(256) void bhist(const int4* __restrict__ rows4,
                                             int* __restrict__ bcnt) {
    __shared__ int lcnt[NBUK];
    for (int b = threadIdx.x; b < NBUK; b += 256) lcnt[b] = 0;
    __syncthreads();
    const int q0 = blockIdx.x * (EPB / 4);
#pragma unroll
    for (int k = 0; k < EPB / 1024; ++k) {
        int q = q0 + k * 256 + threadIdx.x;
        if (q < NE / 4) {
            int4 r = rows4[q];
            atomicAdd(&lcnt[r.x >> BSHIFT], 1);
            atomicAdd(&lcnt[r.y >> BSHIFT], 1);
            atomicAdd(&lcnt[r.z >> BSHIFT], 1);
            atomicAdd(&lcnt[r.w >> BSHIFT], 1);
        }
    }
    __syncthreads();
    for (int b = threadIdx.x; b < NBUK; b += 256) {
        int c = lcnt[b];
        if (c) atomicAdd(&bcnt[b], c);
    }
}

__global__ __launch_bounds__(1024) void bscan(const int* __restrict__ bcnt,
                                              int* __restrict__ bsc,
                                              int* __restrict__ gcur) {
    __shared__ int buf[1024];
    __shared__ int carry;
    int total = 0;
    const int t = threadIdx.x;
    for (int base = 0; base < NBUK; base += 1024) {
        int idx = base + t;
        int v = (idx < NBUK) ? bcnt[idx] : 0;
        buf[t] = v;
        __syncthreads();
        for (int off = 1; off < 1024; off <<= 1) {
            int x = (t >= off) ? buf[t - off] : 0;
            __syncthreads();
            buf[t] += x;
            __syncthreads();
        }
        if (idx < NBUK) {
            int excl = total + buf[t] - v;
            bsc[idx]  = excl;
            gcur[idx] = excl;
        }
        if (t == 1023) carry = buf[1023];
        __syncthreads();
        total += carry;
        __syncthreads();
    }
    if (t == 0) bsc[NBUK] = total;          // == NE
}

__global__ __launch_bounds__(256) void part_kernel(const int4* __restrict__ rows4,
                                                   const int4* __restrict__ cols4,
                                                   const float4* __restrict__ vals4,
                                                   int* __restrict__ gcur,
                                                   uint2* __restrict__ part) {
    __shared__ int lcnt[NBUK];
    __shared__ int lbase[NBUK];
    for (int b = threadIdx.x; b < NBUK; b += 256) lcnt[b] = 0;
    __syncthreads();
    const int q0 = blockIdx.x * (EPB / 4);
    int4 rc[EPB / 1024];
#pragma unroll
    for (int k = 0; k < EPB / 1024; ++k) {
        int q = q0 + k * 256 + threadIdx.x;
        if (q < NE / 4) {
            int4 r = rows4[q];
            rc[k] = r;
            atomicAdd(&lcnt[r.x >> BSHIFT], 1);
            atomicAdd(&lcnt[r.y >> BSHIFT], 1);
            atomicAdd(&lcnt[r.z >> BSHIFT], 1);
            atomicAdd(&lcnt[r.w >> BSHIFT], 1);
        } else {
            rc[k] = make_int4(-1, -1, -1, -1);
        }
    }
    __syncthreads();
    for (int b = threadIdx.x; b < NBUK; b += 256) {
        int c = lcnt[b];
        lbase[b] = c ? atomicAdd(&gcur[b], c) : 0;
        lcnt[b] = 0;                       // reset for rank assignment
    }
    __syncthreads();
#pragma unroll
    for (int k = 0; k < EPB / 1024; ++k) {
        int q = q0 + k * 256 + threadIdx.x;
        if (q < NE / 4) {
            int4   c4 = cols4[q];
            float4 v4 = vals4[q];
            int r, b, rk;
            uint2 rec;
            r = rc[k].x; b = r >> BSHIFT; rk = atomicAdd(&lcnt[b], 1);
            rec.x = ((u32)(r & (BROWS - 1)) << 18) | (u32)c4.x;
            rec.y = __float_as_uint(v4.x);  part[lbase[b] + rk] = rec;
            r = rc[k].y; b = r >> BSHIFT; rk = atomicAdd(&lcnt[b], 1);
            rec.x = ((u32)(r & (BROWS - 1)) << 18) | (u32)c4.y;
            rec.y = __float_as_uint(v4.y);  part[lbase[b] + rk] = rec;
            r = rc[k].z; b = r >> BSHIFT; rk = atomicAdd(&lcnt[b], 1);
            rec.x = ((u32)(r & (BROWS - 1)) << 18) | (u32)c4.z;
            rec.y = __float_as_uint(v4.z);  part[lbase[b] + rk] = rec;
            r = rc[k].w; b = r >> BSHIFT; rk = atomicAdd(&lcnt[b], 1);
            rec.x = ((u32)(r & (BROWS - 1)) << 18) | (u32)c4.w;
            rec.y = __float_as_uint(v4.w);  part[lbase[b] + rk] = rec;
        }
    }
}

// ---------------------------------------------------------------------------
// init_misc = build_t0 (blocks 0..12499) + weight transpose (blocks 12500+).
// t0 = bf16(concat(ue,ee)); wt layout (ushort): wg0T@0 wb0T@4096 wg1T@8192
// wb1T@10240 wg2T@12288 wb2T@12800 (total 13312), all [n][k] k-contiguous.
// ---------------------------------------------------------------------------
__global__ __launch_bounds__(256) void init_misc(
        const float* __restrict__ ue, const float* __restrict__ ee,
        unsigned short* __restrict__ t0,
        const float* __restrict__ Wg0, const float* __restrict__ Wb0,
        const float* __restrict__ Wg1, const float* __restrict__ Wb1,
        const float* __restrict__ Wg2, const float* __restrict__ Wb2,
        unsigned short* __restrict__ wt) {
    if (blockIdx.x < T0_BLKS) {
        int i = blockIdx.x * 256 + threadIdx.x;          // float4 index
        const int uelems = N_USERS * 64 / 4;
        float4 v = (i < uelems) ? ((const float4*)ue)[i]
                                : ((const float4*)ee)[i - uelems];
        ushort4 o;
        o.x = f2bf(v.x); o.y = f2bf(v.y); o.z = f2bf(v.z); o.w = f2bf(v.w);
        ((ushort4*)t0)[i] = o;
        return;
    }
    int idx = (blockIdx.x - T0_BLKS) * 256 + threadIdx.x;
    if (idx < 4096) {                       // Wg0: 64x64
        int k = idx >> 6, n = idx & 63;
        wt[0 + n * 64 + k] = f2bf(Wg0[idx]);
    } else if (idx < 8192) {                // Wb0: 64x64
        int r = idx - 4096; int k = r >> 6, n = r & 63;
        wt[4096 + n * 64 + k] = f2bf(Wb0[r]);
    } else if (idx < 10240) {               // Wg1: 64x32
        int r = idx - 8192; int k = r >> 5, n = r & 31;
        wt[8192 + n * 64 + k] = f2bf(Wg1[r]);
    } else if (idx < 12288) {               // Wb1: 64x32
        int r = idx - 10240; int k = r >> 5, n = r & 31;
        wt[10240 + n * 64 + k] = f2bf(Wb1[r]);
    } else if (idx < 12800) {               // Wg2: 32x16
        int r = idx - 12288; int k = r >> 4, n = r & 15;
        wt[12288 + n * 32 + k] = f2bf(Wg2[r]);
    } else if (idx < 13312) {               // Wb2: 32x16
        int r = idx - 12800; int k = r >> 4, n = r & 15;
        wt[12800 + n * 32 + k] = f2bf(Wb2[r]);
    }
}

// ===========================================================================
// Bucket-resident fused layer (r6): one block per 128-row bucket, 512 threads.
// Phase 0: zero LDS fp32 side[128][DIN].
// Phase 1: edge-centric scatter: half-wave (DIN=64) / quarter-wave (DIN=32)
//          per edge, exact edge count (no ceil waste, no selects, no per-row
//          loop), accumulate v * t[col] into side via LDS atomicAdd
//          (ds_add_f32). 16 edges in flight per wave.
// Phase 2: in-place convert: read side+ego -> regs, barrier, write bf16 H/P
//          tiles aliased onto the same LDS (XOR-swizzled, T2) -> LDS stays
//          32 KB -> 4 blocks/CU (32 waves/CU).
// Phase 3: MFMA transform per 16-row tile (1 tile/wave), epilogue + norms.
// EGO: 0 = ue/ee fp32 (L0), 1 = xin fp32 (L1), 2 = tin bf16 (L2).
// mfma_f32_16x16x32_bf16: A[row=l&15][k=(l>>4)*8+j], B[k][col=l&15],
// D col=l&15, row=(l>>4)*4+reg  (layout verified rounds 1-5).
// ===========================================================================
template <int DIN, int DOUT, int EGO, int WX>
__global__ __launch_bounds__(512) void layer_bucket(
        const uint2* __restrict__ part, const int* __restrict__ bsc,
        const unsigned short* __restrict__ tin,
        const float* __restrict__ ue, const float* __restrict__ ee,
        const float* __restrict__ xin,
        const unsigned short* __restrict__ WgT,   // bf16 [DOUT][DIN]
        const unsigned short* __restrict__ WbT,
        const float* __restrict__ bg, const float* __restrict__ bb,
        float* __restrict__ xout,                 // fp32 [N][DOUT] (if WX)
        unsigned short* __restrict__ tout,        // bf16 [N][DOUT]
        float* __restrict__ norm_out) {
    constexpr int NTC = DOUT / 16;                // col tiles
    constexpr int KS  = DIN / 32;                 // MFMA K-steps
    constexpr int SWZ = (DIN == 64) ? 7 : 3;      // H/P row swizzle mask
    constexpr int TD  = DIN / 4;                  // dims per thread (phase 2)
    constexpr int NQ  = TD / 4;                   // float4s per thread

    __shared__ float side[BROWS * DIN];           // 32 KB (DIN=64) / 16 KB
    u32* Hb32 = (u32*)side;                       // bf16 H [BROWS][DIN] alias
    u32* Pb32 = Hb32 + BROWS * DIN / 2;           // bf16 P alias (2nd half)

    const int tid     = threadIdx.x;
    const int lane    = tid & 63;
    const int wave    = tid >> 6;
    const int rowbase = blockIdx.x * BROWS;

    // ---- phase 0: zero side ----
    {
        float4 z = {0.f, 0.f, 0.f, 0.f};
        for (int j = tid; j < BROWS * DIN / 4; j += 512) ((float4*)side)[j] = z;
    }
    __syncthreads();

    // ---- phase 1: edge scatter-accumulate ----
    const int s = bsc[blockIdx.x];
    const int e = bsc[blockIdx.x + 1];
    if (DIN == 64) {
        const int g  = lane >> 5;                 // half-wave = one edge
        const int d2 = lane & 31;                 // bf16-pair index
        const u32* t32 = (const u32*)tin;
        auto body = [&](int ei) {
            uint2 rec = part[ei];
            int lrow = (int)(rec.x >> 18);
            int col  = (int)(rec.x & 0x3FFFF);
            float v  = __uint_as_float(rec.y);
            u32 x = t32[col * 32 + d2];
            int sidx = lrow * 64 + d2 * 2;
            atomicAdd(&side[sidx],     v * bflo(x));
            atomicAdd(&side[sidx + 1], v * bfhi(x));
        };
        int i = s + wave * 16;
        for (; i + 16 <= e; i += 128) {           // 16 edges/iter, exact
#pragma unroll
            for (int k = 0; k < 8; ++k) body(i + k * 2 + g);
        }
        if (i < e) {                              // tail (once per wave)
#pragma unroll
            for (int k = 0; k < 8; ++k) {
                int ei = i + k * 2 + g;
                if (ei < e) body(ei);
            }
        }
    } else {                                      // DIN == 32
        const int g  = lane >> 4;                 // quarter-wave = one edge
        const int d2 = lane & 15;
        const u32* t16 = (const u32*)tin;
        auto body = [&](int ei) {
            uint2 rec = part[ei];
            int lrow = (int)(rec.x >> 18);
            int col  = (int)(rec.x & 0x3FFFF);
            float v  = __uint_as_float(rec.y);
            u32 x = t16[col * 16 + d2];
            int sidx = lrow * 32 + d2 * 2;
            atomicAdd(&side[sidx],     v * bflo(x));
            atomicAdd(&side[sidx + 1], v * bfhi(x));
        };
        int i = s + wave * 16;
        for (; i + 16 <= e; i += 128) {
#pragma unroll
            for (int k = 0; k < 4; ++k) body(i + k * 4 + g);
        }
        if (i < e) {
#pragma unroll
            for (int k = 0; k < 4; ++k) {
                int ei = i + k * 4 + g;
                if (ei < e) body(ei);
            }
        }
    }
    __syncthreads();

    // ---- phase 2: side + ego -> bf16 H/P (in place, read-sync-write) ----
    {
        const int prow = tid >> 2;                // 0..127
        const int qh   = tid & 3;                 // quarter of dims
        const int grow = rowbase + prow;
        const bool valid = (grow < N_NODES);
        float sv[TD], ev[TD];
        // side reads, q rotated by row to spread LDS bank groups
#pragma unroll
        for (int q0 = 0; q0 < NQ; ++q0) {
            int q = (q0 + prow) & (NQ - 1);
            float4 vv = *(const float4*)&side[prow * DIN + qh * TD + q * 4];
            sv[q * 4 + 0] = vv.x; sv[q * 4 + 1] = vv.y;
            sv[q * 4 + 2] = vv.z; sv[q * 4 + 3] = vv.w;
        }
        if (EGO == 0) {
            const float* src = (grow < N_USERS)
                ? ue + (size_t)grow * 64 : ee + (size_t)(grow - N_USERS) * 64;
#pragma unroll
            for (int q = 0; q < NQ; ++q) {
                float4 vv = valid ? *(const float4*)(src + qh * TD + q * 4)
                                  : (float4){0.f, 0.f, 0.f, 0.f};
                ev[q * 4 + 0] = vv.x; ev[q * 4 + 1] = vv.y;
                ev[q * 4 + 2] = vv.z; ev[q * 4 + 3] = vv.w;
            }
        } else if (EGO == 1) {
            const float* src = xin + (size_t)grow * DIN;
#pragma unroll
            for (int q = 0; q < NQ; ++q) {
                float4 vv = valid ? *(const float4*)(src + qh * TD + q * 4)
                                  : (float4){0.f, 0.f, 0.f, 0.f};
                ev[q * 4 + 0] = vv.x; ev[q * 4 + 1] = vv.y;
                ev[q * 4 + 2] = vv.z; ev[q * 4 + 3] = vv.w;
            }
        } else {                                  // bf16 table ego
            const u32* src = (const u32*)tin + (size_t)grow * (DIN / 2) + qh * (TD / 2);
#pragma unroll
            for (int j = 0; j < TD / 2; ++j) {
                u32 tv = valid ? src[j] : 0;
                ev[2 * j]     = bflo(tv);
                ev[2 * j + 1] = bfhi(tv);
            }
        }
        __syncthreads();                          // ALL side reads done
        u32 hw[TD / 2], pw[TD / 2];
#pragma unroll
        for (int j = 0; j < TD / 2; ++j) {
            hw[j] = cvtpk(ev[2 * j] + sv[2 * j], ev[2 * j + 1] + sv[2 * j + 1]);
            pw[j] = cvtpk(ev[2 * j] * sv[2 * j], ev[2 * j + 1] * sv[2 * j + 1]);
        }
#pragma unroll
        for (int j4 = 0; j4 < TD / 8; ++j4) {     // uint4 (16 B) swizzled writes
            int byteo = (prow * (DIN / 8) + qh * (TD / 8) + j4) * 16;
            byteo ^= ((prow & SWZ) << 4);
            uint4 ho, po;
            ho.x = hw[j4 * 4 + 0]; ho.y = hw[j4 * 4 + 1];
            ho.z = hw[j4 * 4 + 2]; ho.w = hw[j4 * 4 + 3];
            po.x = pw[j4 * 4 + 0]; po.y = pw[j4 * 4 + 1];
            po.z = pw[j4 * 4 + 2]; po.w = pw[j4 * 4 + 3];
            *(uint4*)((char*)Hb32 + byteo) = ho;
            *(uint4*)((char*)Pb32 + byteo) = po;
        }
    }
    __syncthreads();

    // ---- phase 3: MFMA transform, 1 row-tile per wave ----
    {
        const int r16 = lane & 15;
        const int g4  = lane >> 4;
        const int rt  = wave;                     // BROWS/16 == 8 tiles
        const int arow = rt * 16 + r16;
        bf16x8 ah[KS], ap[KS];
#pragma unroll
        for (int sk = 0; sk < KS; ++sk) {
            int ab = (arow * DIN + g4 * 8 + sk * 32) * 2;
            ab ^= ((arow & SWZ) << 4);            // match phase-2 swizzle
            ah[sk] = *(const bf16x8*)((const char*)Hb32 + ab);
            ap[sk] = *(const bf16x8*)((const char*)Pb32 + ab);
        }
        float ss[4] = {0.f, 0.f, 0.f, 0.f};
#pragma unroll
        for (int ct = 0; ct < NTC; ++ct) {
            f32x4 accg = (f32x4){0.f, 0.f, 0.f, 0.f};
            f32x4 accb = (f32x4){0.f, 0.f, 0.f, 0.f};
#pragma unroll
            for (int sk = 0; sk < KS; ++sk) {
                const int boff = (ct * 16 + r16) * DIN + g4 * 8 + sk * 32;
                bf16x8 bgf = *(const bf16x8*)(WgT + boff);
                bf16x8 bbf = *(const bf16x8*)(WbT + boff);
                accg = __builtin_amdgcn_mfma_f32_16x16x32_bf16(ah[sk], bgf, accg, 0, 0, 0);
                accb = __builtin_amdgcn_mfma_f32_16x16x32_bf16(ap[sk], bbf, accb, 0, 0, 0);
            }
            const int col = ct * 16 + r16;
            const float bgv = bg[col];
            const float bbv = bb[col];
#pragma unroll
            for (int r = 0; r < 4; ++r) {
                float a = accg[r] + bgv; a = a > 0.f ? a : 0.01f * a;
                float b = accb[r] + bbv; b = b > 0.f ? b : 0.01f * b;
                float nv = a + b;
                const int row = rowbase + rt * 16 + g4 * 4 + r;
                if (row < N_NODES) {
                    if (WX) xout[(size_t)row * DOUT + col] = nv;
                    tout[(size_t)row * DOUT + col] = f2bf(nv);
                }
                ss[r] += nv * nv;
            }
        }
#pragma unroll
        for (int off = 1; off < 16; off <<= 1) {
#pragma unroll
            for (int r = 0; r < 4; ++r) ss[r] += __shfl_xor(ss[r], off);
        }
        float sv2 = ss[0];
        sv2 = (r16 == 1) ? ss[1] : sv2;
        sv2 = (r16 == 2) ? ss[2] : sv2;
        sv2 = (r16 == 3) ? ss[3] : sv2;
        const int nrow = rowbase + rt * 16 + g4 * 4 + r16;
        if (r16 < 4 && nrow < N_NODES)
            norm_out[nrow] = fmaxf(sqrtf(sv2), 1e-12f);
    }
}

// ===========================================================================
// Scoring: one wave per batch element; sections 64 raw + 64 (e1 fp32) +
// 32 (t2 bf16) + 16 (t3 bf16); normalization folded as 1/(norm products).
// ===========================================================================
__global__ __launch_bounds__(256) void score_kernel(
        const int* __restrict__ users, const int* __restrict__ pos,
        const int* __restrict__ neg,
        const float* __restrict__ ue, const float* __restrict__ ee,
        const float* __restrict__ e1, const float* __restrict__ n0,
        const unsigned short* __restrict__ t2, const float* __restrict__ n1,
        const unsigned short* __restrict__ t3, const float* __restrict__ n2,
        float* __restrict__ out) {
    int gid  = blockIdx.x * 256 + threadIdx.x;
    int idx  = gid >> 6;
    int lane = gid & 63;
    if (idx >= BATCH) return;
    int u  = users[idx];
    int pe = pos[idx];
    int ne = neg[idx];
    int pn = N_USERS + pe;
    int nn = N_USERS + ne;

    float s1p = 1.0f / (n0[u] * n0[pn]);
    float s1n = 1.0f / (n0[u] * n0[nn]);
    float s2p = 1.0f / (n1[u] * n1[pn]);
    float s2n = 1.0f / (n1[u] * n1[nn]);
    float s3p = 1.0f / (n2[u] * n2[pn]);
    float s3n = 1.0f / (n2[u] * n2[nn]);

    float ap = 0.f, an = 0.f;
    {
        float xu = ue[(size_t)u * 64 + lane];
        ap += xu * ee[(size_t)pe * 64 + lane];
        an += xu * ee[(size_t)ne * 64 + lane];
    }
    {
        float xu = e1[(size_t)u * 64 + lane];
        ap += xu * e1[(size_t)pn * 64 + lane] * s1p;
        an += xu * e1[(size_t)nn * 64 + lane] * s1n;
    }
    if (lane < 32) {
        float xu = bf2f(t2[(size_t)u * 32 + lane]);
        ap += xu * bf2f(t2[(size_t)pn * 32 + lane]) * s2p;
        an += xu * bf2f(t2[(size_t)nn * 32 + lane]) * s2n;
    } else if (lane < 48) {
        int d = lane - 32;
        float xu = bf2f(t3[(size_t)u * 16 + d]);
        ap += xu * bf2f(t3[(size_t)pn * 16 + d]) * s3p;
        an += xu * bf2f(t3[(size_t)nn * 16 + d]) * s3n;
    }
#pragma unroll
    for (int off = 32; off > 0; off >>= 1) {
        ap += __shfl_xor(ap, off);
        an += __shfl_xor(an, off);
    }
    if (lane == 0) {
        out[2 * idx + 0] = ap;
        out[2 * idx + 1] = an;
    }
}

// ===========================================================================
extern "C" void kernel_launch(void* const* d_in, const int* in_sizes, int n_in,
                              void* d_out, int out_size, void* d_ws, size_t ws_size,
                              hipStream_t stream) {
    const int*   users = (const int*)d_in[0];
    const int*   pos   = (const int*)d_in[1];
    const int*   neg   = (const int*)d_in[2];
    const int*   rows  = (const int*)d_in[3];
    const int*   cols  = (const int*)d_in[4];
    const float* vals  = (const float*)d_in[5];
    const float* ue    = (const float*)d_in[6];
    const float* ee    = (const float*)d_in[7];
    const float* Wg0 = (const float*)d_in[8],  *bg0 = (const float*)d_in[9];
    const float* Wb0 = (const float*)d_in[10], *bb0 = (const float*)d_in[11];
    const float* Wg1 = (const float*)d_in[12], *bg1 = (const float*)d_in[13];
    const float* Wb1 = (const float*)d_in[14], *bb1 = (const float*)d_in[15];
    const float* Wg2 = (const float*)d_in[16], *bg2 = (const float*)d_in[17];
    const float* Wb2 = (const float*)d_in[18], *bb2 = (const float*)d_in[19];

    // workspace (~130 MB; >=192 MB proven available).
    // NOTE: part no longer aliases e1 (all three layers re-read it).
    float* e1   = (float*)d_ws;                          // N x 64 fp32 (unnorm L1 out)
    float* n0   = e1 + (size_t)N_NODES * 64;             // N
    float* n1   = n0 + N_NODES;                          // N
    float* n2   = n1 + N_NODES;                          // N
    uint2* part = (uint2*)(n2 + N_NODES);                // E records {(lrow<<18)|col, val}
    unsigned short* tA = (unsigned short*)(part + NE);   // N x 64 bf16 (t0, then t2)
    unsigned short* tB = tA + (size_t)N_NODES * 64;      // N x 64 bf16 (t1)
    unsigned short* t3 = tB + (size_t)N_NODES * 64;      // N x 16 bf16 (L3 out)
    unsigned short* wt = t3 + (size_t)N_NODES * 16;      // 13312 (transposed weights)
    int* bcnt = (int*)(wt + 13312);                      // NBUK
    int* bsc  = bcnt + NBUK;                             // NBUK + 1
    int* gcur = bsc + NBUK + 1;                          // NBUK

    // ---- bucket build (no bfill) + t0 table + weight transpose ----
    hipMemsetAsync(bcnt, 0, NBUK * sizeof(int), stream);
    bhist<<<PBLK, 256, 0, stream>>>((const int4*)rows, bcnt);
    bscan<<<1, 1024, 0, stream>>>(bcnt, bsc, gcur);
    part_kernel<<<PBLK, 256, 0, stream>>>((const int4*)rows, (const int4*)cols,
                                          (const float4*)vals, gcur, part);
    init_misc<<<T0_BLKS + WT_BLKS, 256, 0, stream>>>(ue, ee, tA,
                                                     Wg0, Wb0, Wg1, Wb1, Wg2, Wb2, wt);

    // ---- 3 bucket-resident fused layers ----
    layer_bucket<64, 64, 0, 1><<<NBUK, 512, 0, stream>>>(
        part, bsc, tA, ue, ee, nullptr, wt, wt + 4096, bg0, bb0, e1, tB, n0);
    layer_bucket<64, 32, 1, 0><<<NBUK, 512, 0, stream>>>(
        part, bsc, tB, ue, ee, e1, wt + 8192, wt + 10240, bg1, bb1, nullptr, tA, n1);
    layer_bucket<32, 16, 2, 0><<<NBUK, 512, 0, stream>>>(
        part, bsc, tA, ue, ee, nullptr, wt + 12288, wt + 12800, bg2, bb2, nullptr, t3, n2);

    // ---- scoring ----
    score_kernel<<<(BATCH * 64) / 256, 256, 0, stream>>>(users, pos, neg, ue, ee,
                                                         e1, n0, tA, n1, t3, n2,
                                                         (float*)d_out);
}

// Round 7
// 692.521 us; speedup vs baseline: 2.9738x; 2.9738x over previous
//
#include <hip/hip_runtime.h>

#define N_USERS 50000
#define N_ENT   150000
#define N_NODES 200000
#define NE      2000000
#define BATCH   8192

// bucket sort params: 512 rows per bucket
#define BSHIFT 9
#define BROWS  512
#define NBUK   391            // ceil(200000 / 512)
#define EPB    8192           // edges per block in hist/partition
#define PBLK   245            // ceil(NE / EPB)
#define T0_BLKS 12500         // N_NODES*64/4 / 256
#define WT_BLKS 52            // ceil(13312 / 256)

typedef __attribute__((ext_vector_type(8))) short   bf16x8;
typedef __attribute__((ext_vector_type(4))) float   f32x4;
typedef unsigned int u32;

__device__ __forceinline__ float bf2f(unsigned short b) {
    return __uint_as_float(((u32)b) << 16);
}
__device__ __forceinline__ float bflo(u32 x) {          // low bf16 of a pair
    return __uint_as_float(x << 16);
}
__device__ __forceinline__ float bfhi(u32 x) {          // high bf16 of a pair
    return __uint_as_float(x & 0xFFFF0000u);
}
__device__ __forceinline__ unsigned short f2bf(float f) {
    u32 u = __float_as_uint(f);
    u += 0x7FFF + ((u >> 16) & 1);          // round-to-nearest-even
    return (unsigned short)(u >> 16);
}
// pack 2 f32 -> 1 u32 of 2 bf16 (RNE), single instruction on gfx950.
// Verified numerically identical to f2bf pair in round 6 (same absmax).
__device__ __forceinline__ u32 cvtpk(float lo, float hi) {
    u32 r;
    asm("v_cvt_pk_bf16_f32 %0, %1, %2" : "=v"(r) : "v"(lo), "v"(hi));
    return r;
}

// ===========================================================================
// CSR build via 2-level bucket sort (r3-verified structure):
//   bhist: LDS histogram of bucket (row>>9) counts       (int4 streamed)
//   bscan: exclusive scan of 391 bucket counts
//   part_kernel: partition edges bucket-contiguous       (int4/float4 streamed)
//   bfill: per-bucket LDS row-hist + scan -> rs/deg, LDS-cursor CSR fill
// NOTE (r6 lesson): do NOT replace bfill with per-edge LDS float atomics in
// the layer kernels — LDS fp32 atomicAdd serializes at DS-atomic latency
// (758 us/layer, all pipes <5% busy).
// ===========================================================================
__global__ __launch_bounds__(256) void bhist(const int4* __restrict__ rows4,
                                             int* __restrict__ bcnt) {
    __shared__ int lcnt[NBUK];
    for (int b = threadIdx.x; b < NBUK; b += 256) lcnt[b] = 0;
    __syncthreads();
    const int q0 = blockIdx.x * (EPB / 4);
#pragma unroll
    for (int k = 0; k < EPB / 1024; ++k) {
        int q = q0 + k * 256 + threadIdx.x;
        if (q < NE / 4) {
            int4 r = rows4[q];
            atomicAdd(&lcnt[r.x >> BSHIFT], 1);
            atomicAdd(&lcnt[r.y >> BSHIFT], 1);
            atomicAdd(&lcnt[r.z >> BSHIFT], 1);
            atomicAdd(&lcnt[r.w >> BSHIFT], 1);
        }
    }
    __syncthreads();
    for (int b = threadIdx.x; b < NBUK; b += 256) {
        int c = lcnt[b];
        if (c) atomicAdd(&bcnt[b], c);
    }
}

__global__ __launch_bounds__(512) void bscan(const int* __restrict__ bcnt,
                                             int* __restrict__ bsc,
                                             int* __restrict__ gcur) {
    __shared__ int buf[512];
    int t = threadIdx.x;
    int v = (t < NBUK) ? bcnt[t] : 0;
    buf[t] = v;
    __syncthreads();
    for (int off = 1; off < 512; off <<= 1) {
        int x = (t >= off) ? buf[t - off] : 0;
        __syncthreads();
        buf[t] += x;
        __syncthreads();
    }
    if (t < NBUK) {
        int excl = buf[t] - v;
        bsc[t]  = excl;
        gcur[t] = excl;
    }
    if (t == NBUK - 1) bsc[NBUK] = buf[t];   // == NE
}

// partition: records packed {(lrow<<18)|col, val_bits}; each block reserves
// one contiguous run per bucket -> coalesced-ish writes, no hot atomics.
__global__ __launch_bounds__(256) void part_kernel(const int4* __restrict__ rows4,
                                                   const int4* __restrict__ cols4,
                                                   const float4* __restrict__ vals4,
                                                   int* __restrict__ gcur,
                                                   uint2* __restrict__ part) {
    __shared__ int lcnt[NBUK];
    __shared__ int lbase[NBUK];
    for (int b = threadIdx.x; b < NBUK; b += 256) lcnt[b] = 0;
    __syncthreads();
    const int q0 = blockIdx.x * (EPB / 4);
    int4 rc[EPB / 1024];
#pragma unroll
    for (int k = 0; k < EPB / 1024; ++k) {
        int q = q0 + k * 256 + threadIdx.x;
        if (q < NE / 4) {
            int4 r = rows4[q];
            rc[k] = r;
            atomicAdd(&lcnt[r.x >> BSHIFT], 1);
            atomicAdd(&lcnt[r.y >> BSHIFT], 1);
            atomicAdd(&lcnt[r.z >> BSHIFT], 1);
            atomicAdd(&lcnt[r.w >> BSHIFT], 1);
        } else {
            rc[k] = make_int4(-1, -1, -1, -1);
        }
    }
    __syncthreads();
    for (int b = threadIdx.x; b < NBUK; b += 256) {
        int c = lcnt[b];
        lbase[b] = c ? atomicAdd(&gcur[b], c) : 0;
        lcnt[b] = 0;                       // reset for rank assignment
    }
    __syncthreads();
#pragma unroll
    for (int k = 0; k < EPB / 1024; ++k) {
        int q = q0 + k * 256 + threadIdx.x;
        if (q < NE / 4) {
            int4   c4 = cols4[q];
            float4 v4 = vals4[q];
            int r, b, rk;
            uint2 rec;
            r = rc[k].x; b = r >> BSHIFT; rk = atomicAdd(&lcnt[b], 1);
            rec.x = ((u32)(r & (BROWS - 1)) << 18) | (u32)c4.x;
            rec.y = __float_as_uint(v4.x);  part[lbase[b] + rk] = rec;
            r = rc[k].y; b = r >> BSHIFT; rk = atomicAdd(&lcnt[b], 1);
            rec.x = ((u32)(r & (BROWS - 1)) << 18) | (u32)c4.y;
            rec.y = __float_as_uint(v4.y);  part[lbase[b] + rk] = rec;
            r = rc[k].z; b = r >> BSHIFT; rk = atomicAdd(&lcnt[b], 1);
            rec.x = ((u32)(r & (BROWS - 1)) << 18) | (u32)c4.z;
            rec.y = __float_as_uint(v4.z);  part[lbase[b] + rk] = rec;
            r = rc[k].w; b = r >> BSHIFT; rk = atomicAdd(&lcnt[b], 1);
            rec.x = ((u32)(r & (BROWS - 1)) << 18) | (u32)c4.w;
            rec.y = __float_as_uint(v4.w);  part[lbase[b] + rk] = rec;
        }
    }
}

// one block per bucket: row-hist -> LDS scan -> rs/deg, then LDS-cursor fill
__global__ __launch_bounds__(512) void bfill(const uint2* __restrict__ part,
                                             const int* __restrict__ bsc,
                                             int* __restrict__ rs,
                                             int* __restrict__ deg,
                                             uint2* __restrict__ ep) {
    __shared__ int h[BROWS];
    __shared__ int sc[BROWS];
    const int b = blockIdx.x;
    const int t = threadIdx.x;
    const int s = bsc[b];
    const int e = bsc[b + 1];
    h[t] = 0;
    __syncthreads();
    for (int i = s + t; i < e; i += 512)
        atomicAdd(&h[part[i].x >> 18], 1);
    __syncthreads();
    int v = h[t];
    sc[t] = v;
    __syncthreads();
    for (int off = 1; off < 512; off <<= 1) {
        int x = (t >= off) ? sc[t - off] : 0;
        __syncthreads();
        sc[t] += x;
        __syncthreads();
    }
    const int row = b * BROWS + t;
    if (row < N_NODES) {
        deg[row] = v;
        rs[row]  = s + sc[t];              // row_end convention
    }
    h[t] = s + sc[t] - v;                  // cursor = row_start
    __syncthreads();
    for (int i = s + t; i < e; i += 512) {
        uint2 rec = part[i];
        int lr  = rec.x >> 18;
        int pos = atomicAdd(&h[lr], 1);
        uint2 o;
        o.x = rec.x & 0x3FFFF;
        o.y = rec.y;
        ep[pos] = o;                       // bucket slice ~40 KB -> L2-local
    }
}

// ---------------------------------------------------------------------------
// init_misc = build_t0 (blocks 0..12499) + weight transpose (blocks 12500+).
// t0 = bf16(concat(ue,ee)); wt layout (ushort): wg0T@0 wb0T@4096 wg1T@8192
// wb1T@10240 wg2T@12288 wb2T@12800 (total 13312), all [n][k] k-contiguous.
// ---------------------------------------------------------------------------
__global__ __launch_bounds__(256) void init_misc(
        const float* __restrict__ ue, const float* __restrict__ ee,
        unsigned short* __restrict__ t0,
        const float* __restrict__ Wg0, const float* __restrict__ Wb0,
        const float* __restrict__ Wg1, const float* __restrict__ Wb1,
        const float* __restrict__ Wg2, const float* __restrict__ Wb2,
        unsigned short* __restrict__ wt) {
    if (blockIdx.x < T0_BLKS) {
        int i = blockIdx.x * 256 + threadIdx.x;          // float4 index
        const int uelems = N_USERS * 64 / 4;
        float4 v = (i < uelems) ? ((const float4*)ue)[i]
                                : ((const float4*)ee)[i - uelems];
        ushort4 o;
        o.x = f2bf(v.x); o.y = f2bf(v.y); o.z = f2bf(v.z); o.w = f2bf(v.w);
        ((ushort4*)t0)[i] = o;
        return;
    }
    int idx = (blockIdx.x - T0_BLKS) * 256 + threadIdx.x;
    if (idx < 4096) {                       // Wg0: 64x64
        int k = idx >> 6, n = idx & 63;
        wt[0 + n * 64 + k] = f2bf(Wg0[idx]);
    } else if (idx < 8192) {                // Wb0: 64x64
        int r = idx - 4096; int k = r >> 6, n = r & 63;
        wt[4096 + n * 64 + k] = f2bf(Wb0[r]);
    } else if (idx < 10240) {               // Wg1: 64x32
        int r = idx - 8192; int k = r >> 5, n = r & 31;
        wt[8192 + n * 64 + k] = f2bf(Wg1[r]);
    } else if (idx < 12288) {               // Wb1: 64x32
        int r = idx - 10240; int k = r >> 5, n = r & 31;
        wt[10240 + n * 64 + k] = f2bf(Wb1[r]);
    } else if (idx < 12800) {               // Wg2: 32x16
        int r = idx - 12288; int k = r >> 4, n = r & 15;
        wt[12288 + n * 32 + k] = f2bf(Wg2[r]);
    } else if (idx < 13312) {               // Wb2: 32x16
        int r = idx - 12800; int k = r >> 4, n = r & 15;
        wt[12800 + n * 32 + k] = f2bf(Wb2[r]);
    }
}

// ===========================================================================
// Fused layer (r7 = r5 + deeper gather pipeline): gather (wave-per-row,
// scalar CSR, pair loads) -> LDS H/P tile -> MFMA -> epilogue.
// r7 changes vs r5: 16-edge unrolled gather (8 table lines in flight per
// wave for DIN=64, was 4 — attacks the latency/MLP bound; VALU 61%, HBM 36%,
// nothing saturated) and v_cvt_pk_bf16_f32 for the H/P pack.
// EGO: 0 = ue/ee fp32 (L0), 1 = xin fp32 (L1), 2 = tin bf16 (L2).
// mfma_f32_16x16x32_bf16: A[row=l&15][k=(l>>4)*8+j], B[k][col=l&15],
// D col=l&15, row=(l>>4)*4+reg  (layout verified rounds 1-6).
// ===========================================================================
template <int DIN, int DOUT, int EGO, int WX>
__global__ __launch_bounds__(256) void layer_fused(
        const int* __restrict__ rs, const int* __restrict__ deg,
        const uint2* __restrict__ ep,
        const unsigned short* __restrict__ tin,
        const float* __restrict__ ue, const float* __restrict__ ee,
        const float* __restrict__ xin,
        const unsigned short* __restrict__ WgT,   // bf16 [DOUT][DIN]
        const unsigned short* __restrict__ WbT,
        const float* __restrict__ bg, const float* __restrict__ bb,
        float* __restrict__ xout,                 // fp32 [N][DOUT] (if WX)
        unsigned short* __restrict__ tout,        // bf16 [N][DOUT]
        float* __restrict__ norm_out) {
    constexpr int NTC = DOUT / 16;        // col tiles per block
    constexpr int R   = (4 / NTC) * 16;   // rows per block
    constexpr int RPW = R / 4;            // rows gathered per wave
    constexpr int KS  = DIN / 32;

    __shared__ __align__(16) unsigned short sH[R * DIN];
    __shared__ __align__(16) unsigned short sP[R * DIN];
    __shared__ float sPart[R * NTC];

    const int lane    = threadIdx.x & 63;
    const int wave    = threadIdx.x >> 6;
    const int rowbase = blockIdx.x * R;

    // ---- gather phase: wave gathers its RPW rows sequentially ----
    for (int rr = 0; rr < RPW; ++rr) {
        const int lr  = wave * RPW + rr;
        const int row = __builtin_amdgcn_readfirstlane(rowbase + lr);
        const int end   = rs[row];
        const int start = end - deg[row];

        if (DIN == 64) {
            const int g  = lane >> 5;          // edge sub-slot (2 per record pair)
            const int d2 = lane & 31;          // bf16-pair index
            const u32* t32 = (const u32*)tin;
            float axa[4] = {0.f, 0.f, 0.f, 0.f};
            float aya[4] = {0.f, 0.f, 0.f, 0.f};
            for (int i = start; i < end; i += 16) {
                int   cc[16]; float vv[16];
#pragma unroll
                for (int k = 0; k < 16; ++k) {          // scalar (SMEM) loads
                    uint2 rk = ep[i + k];
                    cc[k] = ((u32)rk.x < N_NODES) ? (int)rk.x : 0;
                    vv[k] = (i + k < end) ? __uint_as_float(rk.y) : 0.f;
                }
                u32 xs[8]; float vs[8];
#pragma unroll
                for (int k = 0; k < 8; ++k) {           // 8 lines in flight
                    int cA = g ? cc[2 * k + 1] : cc[2 * k];
                    vs[k]  = g ? vv[2 * k + 1] : vv[2 * k];
                    xs[k]  = t32[(size_t)cA * 32 + d2];
                }
#pragma unroll
                for (int k = 0; k < 8; ++k) {
                    axa[k & 3] = fmaf(vs[k], bflo(xs[k]), axa[k & 3]);
                    aya[k & 3] = fmaf(vs[k], bfhi(xs[k]), aya[k & 3]);
                }
            }
            float ax = (axa[0] + axa[1]) + (axa[2] + axa[3]);
            float ay = (aya[0] + aya[1]) + (aya[2] + aya[3]);
            ax += __shfl_xor(ax, 32);
            ay += __shfl_xor(ay, 32);

            float ex, ey;
            if (EGO == 0) {
                const float2* src = (row < N_USERS)
                    ? (const float2*)ue + (size_t)row * 32
                    : (const float2*)ee + (size_t)(row - N_USERS) * 32;
                float2 ev = src[d2];  ex = ev.x;  ey = ev.y;
            } else if (EGO == 1) {
                float2 ev = ((const float2*)xin)[(size_t)row * 32 + d2];
                ex = ev.x;  ey = ev.y;
            } else {
                u32 tv = t32[(size_t)row * 32 + d2];
                ex = bflo(tv);  ey = bfhi(tv);
            }
            if (g == 0) {
                ((u32*)sH)[lr * 32 + d2] = cvtpk(ex + ax, ey + ay);
                ((u32*)sP)[lr * 32 + d2] = cvtpk(ex * ax, ey * ay);
            }
        } else {   // DIN == 32: quarter-waves, 16 edges/iter, 4 lines in flight
            const int g  = lane >> 4;          // 0..3
            const int d2 = lane & 15;
            const u32* t16 = (const u32*)tin;
            float axa[2] = {0.f, 0.f};
            float aya[2] = {0.f, 0.f};
            for (int i = start; i < end; i += 16) {
                int   cc[16]; float vv[16];
#pragma unroll
                for (int k = 0; k < 16; ++k) {
                    uint2 rk = ep[i + k];
                    cc[k] = ((u32)rk.x < N_NODES) ? (int)rk.x : 0;
                    vv[k] = (i + k < end) ? __uint_as_float(rk.y) : 0.f;
                }
                u32 xs[4]; float vs[4];
#pragma unroll
                for (int k = 0; k < 4; ++k) {
                    int   t0c = (g & 1) ? cc[4 * k + 1] : cc[4 * k];
                    int   t1c = (g & 1) ? cc[4 * k + 3] : cc[4 * k + 2];
                    int   cA  = (g & 2) ? t1c : t0c;
                    float t0v = (g & 1) ? vv[4 * k + 1] : vv[4 * k];
                    float t1v = (g & 1) ? vv[4 * k + 3] : vv[4 * k + 2];
                    vs[k]     = (g & 2) ? t1v : t0v;
                    xs[k]     = t16[(size_t)cA * 16 + d2];
                }
#pragma unroll
                for (int k = 0; k < 4; ++k) {
                    axa[k & 1] = fmaf(vs[k], bflo(xs[k]), axa[k & 1]);
                    aya[k & 1] = fmaf(vs[k], bfhi(xs[k]), aya[k & 1]);
                }
            }
            float ax = axa[0] + axa[1];
            float ay = aya[0] + aya[1];
            ax += __shfl_xor(ax, 32);  ay += __shfl_xor(ay, 32);
            ax += __shfl_xor(ax, 16);  ay += __shfl_xor(ay, 16);

            float ex, ey;
            if (EGO == 2) {
                u32 tv = t16[(size_t)row * 16 + d2];
                ex = bflo(tv);  ey = bfhi(tv);
            } else if (EGO == 1) {
                float2 ev = ((const float2*)xin)[(size_t)row * 16 + d2];
                ex = ev.x;  ey = ev.y;
            } else {
                const float2* src = (row < N_USERS)
                    ? (const float2*)ue + (size_t)row * 32
                    : (const float2*)ee + (size_t)(row - N_USERS) * 32;
                float2 ev = src[d2];  ex = ev.x;  ey = ev.y;
            }
            if (g == 0) {
                ((u32*)sH)[lr * 16 + d2] = cvtpk(ex + ax, ey + ay);
                ((u32*)sP)[lr * 16 + d2] = cvtpk(ex * ax, ey * ay);
            }
        }
    }
    __syncthreads();

    // ---- MFMA phase: wave (rt, ct) computes 16 rows x 16 cols ----
    const int ct  = wave % NTC;
    const int rt  = wave / NTC;
    const int r16 = lane & 15;
    const int g4  = lane >> 4;

    bf16x8 ah[KS], ap[KS];
#pragma unroll
    for (int s = 0; s < KS; ++s) {
        const int aoff = (rt * 16 + r16) * DIN + g4 * 8 + s * 32;
        ah[s] = *reinterpret_cast<const bf16x8*>(sH + aoff);
        ap[s] = *reinterpret_cast<const bf16x8*>(sP + aoff);
    }
    f32x4 accg = (f32x4){0.f, 0.f, 0.f, 0.f};
    f32x4 accb = (f32x4){0.f, 0.f, 0.f, 0.f};
#pragma unroll
    for (int s = 0; s < KS; ++s) {
        const int boff = (ct * 16 + r16) * DIN + g4 * 8 + s * 32;
        bf16x8 bgf = *reinterpret_cast<const bf16x8*>(WgT + boff);
        bf16x8 bbf = *reinterpret_cast<const bf16x8*>(WbT + boff);
        accg = __builtin_amdgcn_mfma_f32_16x16x32_bf16(ah[s], bgf, accg, 0, 0, 0);
        accb = __builtin_amdgcn_mfma_f32_16x16x32_bf16(ap[s], bbf, accb, 0, 0, 0);
    }

    // epilogue: bias + leaky + sum, stores, per-row norm partials
    const int col = ct * 16 + r16;
    const float bgv = bg[col];
    const float bbv = bb[col];
    float ss[4];
#pragma unroll
    for (int r = 0; r < 4; ++r) {
        float a = accg[r] + bgv; a = a > 0.f ? a : 0.01f * a;
        float b = accb[r] + bbv; b = b > 0.f ? b : 0.01f * b;
        float nv = a + b;
        const int row = rowbase + rt * 16 + g4 * 4 + r;
        if (WX) xout[(size_t)row * DOUT + col] = nv;
        tout[(size_t)row * DOUT + col] = f2bf(nv);
        ss[r] = nv * nv;
    }
#pragma unroll
    for (int off = 1; off < 16; off <<= 1) {
#pragma unroll
        for (int r = 0; r < 4; ++r) ss[r] += __shfl_xor(ss[r], off);
    }
    if (r16 == 0) {
#pragma unroll
        for (int r = 0; r < 4; ++r)
            sPart[(rt * 16 + g4 * 4 + r) * NTC + ct] = ss[r];
    }
    __syncthreads();
    for (int t = threadIdx.x; t < R; t += 256) {
        float s = 0.f;
#pragma unroll
        for (int j = 0; j < NTC; ++j) s += sPart[t * NTC + j];
        norm_out[rowbase + t] = fmaxf(sqrtf(s), 1e-12f);
    }
}

// ===========================================================================
// Scoring: one wave per batch element; sections 64 raw + 64 (e1 fp32) +
// 32 (t2 bf16) + 16 (t3 bf16); normalization folded as 1/(norm products).
// ===========================================================================
__global__ __launch_bounds__(256) void score_kernel(
        const int* __restrict__ users, const int* __restrict__ pos,
        const int* __restrict__ neg,
        const float* __restrict__ ue, const float* __restrict__ ee,
        const float* __restrict__ e1, const float* __restrict__ n0,
        const unsigned short* __restrict__ t2, const float* __restrict__ n1,
        const unsigned short* __restrict__ t3, const float* __restrict__ n2,
        float* __restrict__ out) {
    int gid  = blockIdx.x * 256 + threadIdx.x;
    int idx  = gid >> 6;
    int lane = gid & 63;
    if (idx >= BATCH) return;
    int u  = users[idx];
    int pe = pos[idx];
    int ne = neg[idx];
    int pn = N_USERS + pe;
    int nn = N_USERS + ne;

    float s1p = 1.0f / (n0[u] * n0[pn]);
    float s1n = 1.0f / (n0[u] * n0[nn]);
    float s2p = 1.0f / (n1[u] * n1[pn]);
    float s2n = 1.0f / (n1[u] * n1[nn]);
    float s3p = 1.0f / (n2[u] * n2[pn]);
    float s3n = 1.0f / (n2[u] * n2[nn]);

    float ap = 0.f, an = 0.f;
    {
        float xu = ue[(size_t)u * 64 + lane];
        ap += xu * ee[(size_t)pe * 64 + lane];
        an += xu * ee[(size_t)ne * 64 + lane];
    }
    {
        float xu = e1[(size_t)u * 64 + lane];
        ap += xu * e1[(size_t)pn * 64 + lane] * s1p;
        an += xu * e1[(size_t)nn * 64 + lane] * s1n;
    }
    if (lane < 32) {
        float xu = bf2f(t2[(size_t)u * 32 + lane]);
        ap += xu * bf2f(t2[(size_t)pn * 32 + lane]) * s2p;
        an += xu * bf2f(t2[(size_t)nn * 32 + lane]) * s2n;
    } else if (lane < 48) {
        int d = lane - 32;
        float xu = bf2f(t3[(size_t)u * 16 + d]);
        ap += xu * bf2f(t3[(size_t)pn * 16 + d]) * s3p;
        an += xu * bf2f(t3[(size_t)nn * 16 + d]) * s3n;
    }
#pragma unroll
    for (int off = 32; off > 0; off >>= 1) {
        ap += __shfl_xor(ap, off);
        an += __shfl_xor(an, off);
    }
    if (lane == 0) {
        out[2 * idx + 0] = ap;
        out[2 * idx + 1] = an;
    }
}

// ===========================================================================
extern "C" void kernel_launch(void* const* d_in, const int* in_sizes, int n_in,
                              void* d_out, int out_size, void* d_ws, size_t ws_size,
                              hipStream_t stream) {
    const int*   users = (const int*)d_in[0];
    const int*   pos   = (const int*)d_in[1];
    const int*   neg   = (const int*)d_in[2];
    const int*   rows  = (const int*)d_in[3];
    const int*   cols  = (const int*)d_in[4];
    const float* vals  = (const float*)d_in[5];
    const float* ue    = (const float*)d_in[6];
    const float* ee    = (const float*)d_in[7];
    const float* Wg0 = (const float*)d_in[8],  *bg0 = (const float*)d_in[9];
    const float* Wb0 = (const float*)d_in[10], *bb0 = (const float*)d_in[11];
    const float* Wg1 = (const float*)d_in[12], *bg1 = (const float*)d_in[13];
    const float* Wb1 = (const float*)d_in[14], *bb1 = (const float*)d_in[15];
    const float* Wg2 = (const float*)d_in[16], *bg2 = (const float*)d_in[17];
    const float* Wb2 = (const float*)d_in[18], *bb2 = (const float*)d_in[19];

    // workspace (~128 MB; >=192 MB proven available)
    float* e1   = (float*)d_ws;                          // N x 64 fp32 (unnorm L1 out)
    float* n0   = e1 + (size_t)N_NODES * 64;             // N
    float* n1   = n0 + N_NODES;                          // N
    float* n2   = n1 + N_NODES;                          // N
    uint2* ep   = (uint2*)(n2 + N_NODES);                // E packed {col, val}
    unsigned short* tA = (unsigned short*)(ep + NE);     // N x 64 bf16 (t0, then t2)
    unsigned short* tB = tA + (size_t)N_NODES * 64;      // N x 64 bf16 (t1)
    unsigned short* t3 = tB + (size_t)N_NODES * 64;      // N x 16 bf16 (L3 out)
    unsigned short* wt = t3 + (size_t)N_NODES * 16;      // 13312 (transposed weights)
    int* deg  = (int*)(wt + 13312);                      // N
    int* rs   = deg + N_NODES;                           // N
    int* bcnt = rs + N_NODES;                            // NBUK
    int* bsc  = bcnt + NBUK;                             // NBUK + 1
    int* gcur = bsc + NBUK + 1;                          // NBUK
    uint2* part = (uint2*)e1;                            // E records (16 MB),
                                                         // reuses e1 (free until
                                                         // layer 0 writes it)

    // ---- CSR build via bucket sort + t0 table + weight transpose ----
    hipMemsetAsync(bcnt, 0, NBUK * sizeof(int), stream);
    bhist<<<PBLK, 256, 0, stream>>>((const int4*)rows, bcnt);
    bscan<<<1, 512, 0, stream>>>(bcnt, bsc, gcur);
    part_kernel<<<PBLK, 256, 0, stream>>>((const int4*)rows, (const int4*)cols,
                                          (const float4*)vals, gcur, part);
    bfill<<<NBUK, 512, 0, stream>>>(part, bsc, rs, deg, ep);
    init_misc<<<T0_BLKS + WT_BLKS, 256, 0, stream>>>(ue, ee, tA,
                                                     Wg0, Wb0, Wg1, Wb1, Wg2, Wb2, wt);

    // ---- 3 fused layers: gather -> LDS -> MFMA -> stores + norm ----
    layer_fused<64, 64, 0, 1><<<N_NODES / 16, 256, 0, stream>>>(
        rs, deg, ep, tA, ue, ee, nullptr, wt, wt + 4096, bg0, bb0, e1, tB, n0);
    layer_fused<64, 32, 1, 0><<<N_NODES / 32, 256, 0, stream>>>(
        rs, deg, ep, tB, ue, ee, e1, wt + 8192, wt + 10240, bg1, bb1, nullptr, tA, n1);
    layer_fused<32, 16, 2, 0><<<N_NODES / 64, 256, 0, stream>>>(
        rs, deg, ep, tA, ue, ee, nullptr, wt + 12288, wt + 12800, bg2, bb2, nullptr, t3, n2);

    // ---- scoring ----
    score_kernel<<<(BATCH * 64) / 256, 256, 0, stream>>>(users, pos, neg, ue, ee,
                                                         e1, n0, tA, n1, t3, n2,
                                                         (float*)d_out);
}

// Round 8
// 446.861 us; speedup vs baseline: 4.6087x; 1.5497x over previous
//
#include <hip/hip_runtime.h>

#define N_USERS 50000
#define N_ENT   150000
#define N_NODES 200000
#define NE      2000000
#define BATCH   8192

// bucket sort params: 512 rows per bucket
#define BSHIFT 9
#define BROWS  512
#define NBUK   391            // ceil(200000 / 512)
#define EPB    8192           // edges per block in hist/partition
#define PBLK   245            // ceil(NE / EPB)
#define T0_BLKS 12500         // N_NODES*64/4 / 256
#define WT_BLKS 52            // ceil(13312 / 256)

typedef __attribute__((ext_vector_type(8))) short   bf16x8;
typedef __attribute__((ext_vector_type(4))) float   f32x4;
typedef unsigned int u32;

__device__ __forceinline__ float bf2f(unsigned short b) {
    return __uint_as_float(((u32)b) << 16);
}
__device__ __forceinline__ float bflo(u32 x) {          // low bf16 of a pair
    return __uint_as_float(x << 16);
}
__device__ __forceinline__ float bfhi(u32 x) {          // high bf16 of a pair
    return __uint_as_float(x & 0xFFFF0000u);
}
__device__ __forceinline__ unsigned short f2bf(float f) {
    u32 u = __float_as_uint(f);
    u += 0x7FFF + ((u >> 16) & 1);          // round-to-nearest-even
    return (unsigned short)(u >> 16);
}
// pack 2 f32 -> 1 u32 of 2 bf16 (RNE), single instruction on gfx950.
// Verified numerically identical to f2bf pair in round 6 (same absmax).
__device__ __forceinline__ u32 cvtpk(float lo, float hi) {
    u32 r;
    asm("v_cvt_pk_bf16_f32 %0, %1, %2" : "=v"(r) : "v"(lo), "v"(hi));
    return r;
}

// ===========================================================================
// CSR build via 2-level bucket sort (r3-verified structure).
// LESSONS carried: (r6) no per-edge LDS float atomics (DS-atomic latency
// serializes, 758 us/layer). (r7) no indexed local arrays in the gather —
// they spill to scratch (WRITE_SIZE 76 MB -> 1.58 GB, 3x regression);
// named scalars ONLY.
// ===========================================================================
__global__ __launch_bounds__(256) void bhist(const int4* __restrict__ rows4,
                                             int* __restrict__ bcnt) {
    __shared__ int lcnt[NBUK];
    for (int b = threadIdx.x; b < NBUK; b += 256) lcnt[b] = 0;
    __syncthreads();
    const int q0 = blockIdx.x * (EPB / 4);
#pragma unroll
    for (int k = 0; k < EPB / 1024; ++k) {
        int q = q0 + k * 256 + threadIdx.x;
        if (q < NE / 4) {
            int4 r = rows4[q];
            atomicAdd(&lcnt[r.x >> BSHIFT], 1);
            atomicAdd(&lcnt[r.y >> BSHIFT], 1);
            atomicAdd(&lcnt[r.z >> BSHIFT], 1);
            atomicAdd(&lcnt[r.w >> BSHIFT], 1);
        }
    }
    __syncthreads();
    for (int b = threadIdx.x; b < NBUK; b += 256) {
        int c = lcnt[b];
        if (c) atomicAdd(&bcnt[b], c);
    }
}

__global__ __launch_bounds__(512) void bscan(const int* __restrict__ bcnt,
                                             int* __restrict__ bsc,
                                             int* __restrict__ gcur) {
    __shared__ int buf[512];
    int t = threadIdx.x;
    int v = (t < NBUK) ? bcnt[t] : 0;
    buf[t] = v;
    __syncthreads();
    for (int off = 1; off < 512; off <<= 1) {
        int x = (t >= off) ? buf[t - off] : 0;
        __syncthreads();
        buf[t] += x;
        __syncthreads();
    }
    if (t < NBUK) {
        int excl = buf[t] - v;
        bsc[t]  = excl;
        gcur[t] = excl;
    }
    if (t == NBUK - 1) bsc[NBUK] = buf[t];   // == NE
}

// partition: records packed {(lrow<<18)|col, val_bits}; each block reserves
// one contiguous run per bucket -> coalesced-ish writes, no hot atomics.
__global__ __launch_bounds__(256) void part_kernel(const int4* __restrict__ rows4,
                                                   const int4* __restrict__ cols4,
                                                   const float4* __restrict__ vals4,
                                                   int* __restrict__ gcur,
                                                   uint2* __restrict__ part) {
    __shared__ int lcnt[NBUK];
    __shared__ int lbase[NBUK];
    for (int b = threadIdx.x; b < NBUK; b += 256) lcnt[b] = 0;
    __syncthreads();
    const int q0 = blockIdx.x * (EPB / 4);
    int4 rc[EPB / 1024];
#pragma unroll
    for (int k = 0; k < EPB / 1024; ++k) {
        int q = q0 + k * 256 + threadIdx.x;
        if (q < NE / 4) {
            int4 r = rows4[q];
            rc[k] = r;
            atomicAdd(&lcnt[r.x >> BSHIFT], 1);
            atomicAdd(&lcnt[r.y >> BSHIFT], 1);
            atomicAdd(&lcnt[r.z >> BSHIFT], 1);
            atomicAdd(&lcnt[r.w >> BSHIFT], 1);
        } else {
            rc[k] = make_int4(-1, -1, -1, -1);
        }
    }
    __syncthreads();
    for (int b = threadIdx.x; b < NBUK; b += 256) {
        int c = lcnt[b];
        lbase[b] = c ? atomicAdd(&gcur[b], c) : 0;
        lcnt[b] = 0;                       // reset for rank assignment
    }
    __syncthreads();
#pragma unroll
    for (int k = 0; k < EPB / 1024; ++k) {
        int q = q0 + k * 256 + threadIdx.x;
        if (q < NE / 4) {
            int4   c4 = cols4[q];
            float4 v4 = vals4[q];
            int r, b, rk;
            uint2 rec;
            r = rc[k].x; b = r >> BSHIFT; rk = atomicAdd(&lcnt[b], 1);
            rec.x = ((u32)(r & (BROWS - 1)) << 18) | (u32)c4.x;
            rec.y = __float_as_uint(v4.x);  part[lbase[b] + rk] = rec;
            r = rc[k].y; b = r >> BSHIFT; rk = atomicAdd(&lcnt[b], 1);
            rec.x = ((u32)(r & (BROWS - 1)) << 18) | (u32)c4.y;
            rec.y = __float_as_uint(v4.y);  part[lbase[b] + rk] = rec;
            r = rc[k].z; b = r >> BSHIFT; rk = atomicAdd(&lcnt[b], 1);
            rec.x = ((u32)(r & (BROWS - 1)) << 18) | (u32)c4.z;
            rec.y = __float_as_uint(v4.z);  part[lbase[b] + rk] = rec;
            r = rc[k].w; b = r >> BSHIFT; rk = atomicAdd(&lcnt[b], 1);
            rec.x = ((u32)(r & (BROWS - 1)) << 18) | (u32)c4.w;
            rec.y = __float_as_uint(v4.w);  part[lbase[b] + rk] = rec;
        }
    }
}

// one block per bucket: row-hist -> LDS scan -> rs/deg, then LDS-cursor fill
__global__ __launch_bounds__(512) void bfill(const uint2* __restrict__ part,
                                             const int* __restrict__ bsc,
                                             int* __restrict__ rs,
                                             int* __restrict__ deg,
                                             uint2* __restrict__ ep) {
    __shared__ int h[BROWS];
    __shared__ int sc[BROWS];
    const int b = blockIdx.x;
    const int t = threadIdx.x;
    const int s = bsc[b];
    const int e = bsc[b + 1];
    h[t] = 0;
    __syncthreads();
    for (int i = s + t; i < e; i += 512)
        atomicAdd(&h[part[i].x >> 18], 1);
    __syncthreads();
    int v = h[t];
    sc[t] = v;
    __syncthreads();
    for (int off = 1; off < 512; off <<= 1) {
        int x = (t >= off) ? sc[t - off] : 0;
        __syncthreads();
        sc[t] += x;
        __syncthreads();
    }
    const int row = b * BROWS + t;
    if (row < N_NODES) {
        deg[row] = v;
        rs[row]  = s + sc[t];              // row_end convention
    }
    h[t] = s + sc[t] - v;                  // cursor = row_start
    __syncthreads();
    for (int i = s + t; i < e; i += 512) {
        uint2 rec = part[i];
        int lr  = rec.x >> 18;
        int pos = atomicAdd(&h[lr], 1);
        uint2 o;
        o.x = rec.x & 0x3FFFF;
        o.y = rec.y;
        ep[pos] = o;                       // bucket slice ~40 KB -> L2-local
    }
}

// ---------------------------------------------------------------------------
// init_misc = build_t0 (blocks 0..12499) + weight transpose (blocks 12500+).
// t0 = bf16(concat(ue,ee)); wt layout (ushort): wg0T@0 wb0T@4096 wg1T@8192
// wb1T@10240 wg2T@12288 wb2T@12800 (total 13312), all [n][k] k-contiguous.
// ---------------------------------------------------------------------------
__global__ __launch_bounds__(256) void init_misc(
        const float* __restrict__ ue, const float* __restrict__ ee,
        unsigned short* __restrict__ t0,
        const float* __restrict__ Wg0, const float* __restrict__ Wb0,
        const float* __restrict__ Wg1, const float* __restrict__ Wb1,
        const float* __restrict__ Wg2, const float* __restrict__ Wb2,
        unsigned short* __restrict__ wt) {
    if (blockIdx.x < T0_BLKS) {
        int i = blockIdx.x * 256 + threadIdx.x;          // float4 index
        const int uelems = N_USERS * 64 / 4;
        float4 v = (i < uelems) ? ((const float4*)ue)[i]
                                : ((const float4*)ee)[i - uelems];
        ushort4 o;
        o.x = f2bf(v.x); o.y = f2bf(v.y); o.z = f2bf(v.z); o.w = f2bf(v.w);
        ((ushort4*)t0)[i] = o;
        return;
    }
    int idx = (blockIdx.x - T0_BLKS) * 256 + threadIdx.x;
    if (idx < 4096) {                       // Wg0: 64x64
        int k = idx >> 6, n = idx & 63;
        wt[0 + n * 64 + k] = f2bf(Wg0[idx]);
    } else if (idx < 8192) {                // Wb0: 64x64
        int r = idx - 4096; int k = r >> 6, n = r & 63;
        wt[4096 + n * 64 + k] = f2bf(Wb0[r]);
    } else if (idx < 10240) {               // Wg1: 64x32
        int r = idx - 8192; int k = r >> 5, n = r & 31;
        wt[8192 + n * 64 + k] = f2bf(Wg1[r]);
    } else if (idx < 12288) {               // Wb1: 64x32
        int r = idx - 10240; int k = r >> 5, n = r & 31;
        wt[10240 + n * 64 + k] = f2bf(Wb1[r]);
    } else if (idx < 12800) {               // Wg2: 32x16
        int r = idx - 12288; int k = r >> 4, n = r & 15;
        wt[12288 + n * 32 + k] = f2bf(Wg2[r]);
    } else if (idx < 13312) {               // Wb2: 32x16
        int r = idx - 12800; int k = r >> 4, n = r & 15;
        wt[12800 + n * 32 + k] = f2bf(Wb2[r]);
    }
}

// ===========================================================================
// Fused layer (r8 = r5 + broadcast record loads + 16-edge named-scalar
// unroll + cvtpk). Gather: wave-per-row; half-wave g loads ITS record
// ep[i+2k+g] directly (per-lane broadcast load, no cndmask slot-selects);
// 8 table lines in flight per wave (was 4). Garbage tail records (reads past
// row end / array end land in ws) handled by v_min_u32 col clamp + uniform
// val zeroing. NAMED SCALARS ONLY (r7: arrays spilled to scratch).
// EGO: 0 = ue/ee fp32 (L0), 1 = xin fp32 (L1), 2 = tin bf16 (L2).
// mfma_f32_16x16x32_bf16: A[row=l&15][k=(l>>4)*8+j], B[k][col=l&15],
// D col=l&15, row=(l>>4)*4+reg  (layout verified rounds 1-6).
// ===========================================================================
template <int DIN, int DOUT, int EGO, int WX>
__global__ __launch_bounds__(256) void layer_fused(
        const int* __restrict__ rs, const int* __restrict__ deg,
        const uint2* __restrict__ ep,
        const unsigned short* __restrict__ tin,
        const float* __restrict__ ue, const float* __restrict__ ee,
        const float* __restrict__ xin,
        const unsigned short* __restrict__ WgT,   // bf16 [DOUT][DIN]
        const unsigned short* __restrict__ WbT,
        const float* __restrict__ bg, const float* __restrict__ bb,
        float* __restrict__ xout,                 // fp32 [N][DOUT] (if WX)
        unsigned short* __restrict__ tout,        // bf16 [N][DOUT]
        float* __restrict__ norm_out) {
    constexpr int NTC = DOUT / 16;        // col tiles per block
    constexpr int R   = (4 / NTC) * 16;   // rows per block
    constexpr int RPW = R / 4;            // rows gathered per wave
    constexpr int KS  = DIN / 32;
    constexpr u32 CMAX = N_NODES - 1;

    __shared__ __align__(16) unsigned short sH[R * DIN];
    __shared__ __align__(16) unsigned short sP[R * DIN];
    __shared__ float sPart[R * NTC];

    const int lane    = threadIdx.x & 63;
    const int wave    = threadIdx.x >> 6;
    const int rowbase = blockIdx.x * R;

    // ---- gather phase: wave gathers its RPW rows sequentially ----
    for (int rr = 0; rr < RPW; ++rr) {
        const int lr  = wave * RPW + rr;
        const int row = __builtin_amdgcn_readfirstlane(rowbase + lr);
        const int end   = rs[row];
        const int start = end - deg[row];

        if (DIN == 64) {
            const int g  = lane >> 5;          // half-wave: edge sub-slot
            const int d2 = lane & 31;          // bf16-pair index
            const u32* t32 = (const u32*)tin;
            float ax0 = 0.f, ax1 = 0.f, ax2 = 0.f, ax3 = 0.f;
            float ay0 = 0.f, ay1 = 0.f, ay2 = 0.f, ay3 = 0.f;
            for (int i = start; i < end; i += 16) {
                // per-lane broadcast record loads (half-wave-uniform addr)
                uint2 q0 = ep[i + 0  + g];
                uint2 q1 = ep[i + 2  + g];
                uint2 q2 = ep[i + 4  + g];
                uint2 q3 = ep[i + 6  + g];
                uint2 q4 = ep[i + 8  + g];
                uint2 q5 = ep[i + 10 + g];
                uint2 q6 = ep[i + 12 + g];
                uint2 q7 = ep[i + 14 + g];
                u32 c0 = min(q0.x, CMAX);
                u32 c1 = min(q1.x, CMAX);
                u32 c2 = min(q2.x, CMAX);
                u32 c3 = min(q3.x, CMAX);
                u32 c4 = min(q4.x, CMAX);
                u32 c5 = min(q5.x, CMAX);
                u32 c6 = min(q6.x, CMAX);
                u32 c7 = min(q7.x, CMAX);
                u32 x0 = t32[(size_t)c0 * 32 + d2];      // 8 lines in flight
                u32 x1 = t32[(size_t)c1 * 32 + d2];
                u32 x2 = t32[(size_t)c2 * 32 + d2];
                u32 x3 = t32[(size_t)c3 * 32 + d2];
                u32 x4 = t32[(size_t)c4 * 32 + d2];
                u32 x5 = t32[(size_t)c5 * 32 + d2];
                u32 x6 = t32[(size_t)c6 * 32 + d2];
                u32 x7 = t32[(size_t)c7 * 32 + d2];
                const int rem = end - i;                 // uniform
                float v0 = (g + 0  < rem) ? __uint_as_float(q0.y) : 0.f;
                float v1 = (g + 2  < rem) ? __uint_as_float(q1.y) : 0.f;
                float v2 = (g + 4  < rem) ? __uint_as_float(q2.y) : 0.f;
                float v3 = (g + 6  < rem) ? __uint_as_float(q3.y) : 0.f;
                float v4 = (g + 8  < rem) ? __uint_as_float(q4.y) : 0.f;
                float v5 = (g + 10 < rem) ? __uint_as_float(q5.y) : 0.f;
                float v6 = (g + 12 < rem) ? __uint_as_float(q6.y) : 0.f;
                float v7 = (g + 14 < rem) ? __uint_as_float(q7.y) : 0.f;
                ax0 = fmaf(v0, bflo(x0), ax0);  ay0 = fmaf(v0, bfhi(x0), ay0);
                ax1 = fmaf(v1, bflo(x1), ax1);  ay1 = fmaf(v1, bfhi(x1), ay1);
                ax2 = fmaf(v2, bflo(x2), ax2);  ay2 = fmaf(v2, bfhi(x2), ay2);
                ax3 = fmaf(v3, bflo(x3), ax3);  ay3 = fmaf(v3, bfhi(x3), ay3);
                ax0 = fmaf(v4, bflo(x4), ax0);  ay0 = fmaf(v4, bfhi(x4), ay0);
                ax1 = fmaf(v5, bflo(x5), ax1);  ay1 = fmaf(v5, bfhi(x5), ay1);
                ax2 = fmaf(v6, bflo(x6), ax2);  ay2 = fmaf(v6, bfhi(x6), ay2);
                ax3 = fmaf(v7, bflo(x7), ax3);  ay3 = fmaf(v7, bfhi(x7), ay3);
            }
            float ax = (ax0 + ax1) + (ax2 + ax3);
            float ay = (ay0 + ay1) + (ay2 + ay3);
            ax += __shfl_xor(ax, 32);
            ay += __shfl_xor(ay, 32);

            float ex, ey;
            if (EGO == 0) {
                const float2* src = (row < N_USERS)
                    ? (const float2*)ue + (size_t)row * 32
                    : (const float2*)ee + (size_t)(row - N_USERS) * 32;
                float2 ev = src[d2];  ex = ev.x;  ey = ev.y;
            } else if (EGO == 1) {
                float2 ev = ((const float2*)xin)[(size_t)row * 32 + d2];
                ex = ev.x;  ey = ev.y;
            } else {
                u32 tv = t32[(size_t)row * 32 + d2];
                ex = bflo(tv);  ey = bfhi(tv);
            }
            if (g == 0) {
                ((u32*)sH)[lr * 32 + d2] = cvtpk(ex + ax, ey + ay);
                ((u32*)sP)[lr * 32 + d2] = cvtpk(ex * ax, ey * ay);
            }
        } else {   // DIN == 32: quarter-waves, 16 edges/iter, 4 lines in flight
            const int g  = lane >> 4;          // 0..3
            const int d2 = lane & 15;
            const u32* t16 = (const u32*)tin;
            float ax0 = 0.f, ax1 = 0.f;
            float ay0 = 0.f, ay1 = 0.f;
            for (int i = start; i < end; i += 16) {
                uint2 q0 = ep[i + 0  + g];
                uint2 q1 = ep[i + 4  + g];
                uint2 q2 = ep[i + 8  + g];
                uint2 q3 = ep[i + 12 + g];
                u32 c0 = min(q0.x, CMAX);
                u32 c1 = min(q1.x, CMAX);
                u32 c2 = min(q2.x, CMAX);
                u32 c3 = min(q3.x, CMAX);
                u32 x0 = t16[(size_t)c0 * 16 + d2];
                u32 x1 = t16[(size_t)c1 * 16 + d2];
                u32 x2 = t16[(size_t)c2 * 16 + d2];
                u32 x3 = t16[(size_t)c3 * 16 + d2];
                const int rem = end - i;
                float v0 = (g + 0  < rem) ? __uint_as_float(q0.y) : 0.f;
                float v1 = (g + 4  < rem) ? __uint_as_float(q1.y) : 0.f;
                float v2 = (g + 8  < rem) ? __uint_as_float(q2.y) : 0.f;
                float v3 = (g + 12 < rem) ? __uint_as_float(q3.y) : 0.f;
                ax0 = fmaf(v0, bflo(x0), ax0);  ay0 = fmaf(v0, bfhi(x0), ay0);
                ax1 = fmaf(v1, bflo(x1), ax1);  ay1 = fmaf(v1, bfhi(x1), ay1);
                ax0 = fmaf(v2, bflo(x2), ax0);  ay0 = fmaf(v2, bfhi(x2), ay0);
                ax1 = fmaf(v3, bflo(x3), ax1);  ay1 = fmaf(v3, bfhi(x3), ay1);
            }
            float ax = ax0 + ax1;
            float ay = ay0 + ay1;
            ax += __shfl_xor(ax, 32);  ay += __shfl_xor(ay, 32);
            ax += __shfl_xor(ax, 16);  ay += __shfl_xor(ay, 16);

            float ex, ey;
            if (EGO == 2) {
                u32 tv = t16[(size_t)row * 16 + d2];
                ex = bflo(tv);  ey = bfhi(tv);
            } else if (EGO == 1) {
                float2 ev = ((const float2*)xin)[(size_t)row * 16 + d2];
                ex = ev.x;  ey = ev.y;
            } else {
                const float2* src = (row < N_USERS)
                    ? (const float2*)ue + (size_t)row * 32
                    : (const float2*)ee + (size_t)(row - N_USERS) * 32;
                float2 ev = src[d2];  ex = ev.x;  ey = ev.y;
            }
            if (g == 0) {
                ((u32*)sH)[lr * 16 + d2] = cvtpk(ex + ax, ey + ay);
                ((u32*)sP)[lr * 16 + d2] = cvtpk(ex * ax, ey * ay);
            }
        }
    }
    __syncthreads();

    // ---- MFMA phase: wave (rt, ct) computes 16 rows x 16 cols ----
    const int ct  = wave % NTC;
    const int rt  = wave / NTC;
    const int r16 = lane & 15;
    const int g4  = lane >> 4;

    bf16x8 ah[KS], ap[KS];
#pragma unroll
    for (int s = 0; s < KS; ++s) {
        const int aoff = (rt * 16 + r16) * DIN + g4 * 8 + s * 32;
        ah[s] = *reinterpret_cast<const bf16x8*>(sH + aoff);
        ap[s] = *reinterpret_cast<const bf16x8*>(sP + aoff);
    }
    f32x4 accg = (f32x4){0.f, 0.f, 0.f, 0.f};
    f32x4 accb = (f32x4){0.f, 0.f, 0.f, 0.f};
#pragma unroll
    for (int s = 0; s < KS; ++s) {
        const int boff = (ct * 16 + r16) * DIN + g4 * 8 + s * 32;
        bf16x8 bgf = *reinterpret_cast<const bf16x8*>(WgT + boff);
        bf16x8 bbf = *reinterpret_cast<const bf16x8*>(WbT + boff);
        accg = __builtin_amdgcn_mfma_f32_16x16x32_bf16(ah[s], bgf, accg, 0, 0, 0);
        accb = __builtin_amdgcn_mfma_f32_16x16x32_bf16(ap[s], bbf, accb, 0, 0, 0);
    }

    // epilogue: bias + leaky + sum, stores, per-row norm partials
    const int col = ct * 16 + r16;
    const float bgv = bg[col];
    const float bbv = bb[col];
    float ss[4];
#pragma unroll
    for (int r = 0; r < 4; ++r) {
        float a = accg[r] + bgv; a = a > 0.f ? a : 0.01f * a;
        float b = accb[r] + bbv; b = b > 0.f ? b : 0.01f * b;
        float nv = a + b;
        const int row = rowbase + rt * 16 + g4 * 4 + r;
        if (WX) xout[(size_t)row * DOUT + col] = nv;
        tout[(size_t)row * DOUT + col] = f2bf(nv);
        ss[r] = nv * nv;
    }
#pragma unroll
    for (int off = 1; off < 16; off <<= 1) {
#pragma unroll
        for (int r = 0; r < 4; ++r) ss[r] += __shfl_xor(ss[r], off);
    }
    if (r16 == 0) {
#pragma unroll
        for (int r = 0; r < 4; ++r)
            sPart[(rt * 16 + g4 * 4 + r) * NTC + ct] = ss[r];
    }
    __syncthreads();
    for (int t = threadIdx.x; t < R; t += 256) {
        float s = 0.f;
#pragma unroll
        for (int j = 0; j < NTC; ++j) s += sPart[t * NTC + j];
        norm_out[rowbase + t] = fmaxf(sqrtf(s), 1e-12f);
    }
}

// ===========================================================================
// Scoring: one wave per batch element; sections 64 raw + 64 (e1 fp32) +
// 32 (t2 bf16) + 16 (t3 bf16); normalization folded as 1/(norm products).
// ===========================================================================
__global__ __launch_bounds__(256) void score_kernel(
        const int* __restrict__ users, const int* __restrict__ pos,
        const int* __restrict__ neg,
        const float* __restrict__ ue, const float* __restrict__ ee,
        const float* __restrict__ e1, const float* __restrict__ n0,
        const unsigned short* __restrict__ t2, const float* __restrict__ n1,
        const unsigned short* __restrict__ t3, const float* __restrict__ n2,
        float* __restrict__ out) {
    int gid  = blockIdx.x * 256 + threadIdx.x;
    int idx  = gid >> 6;
    int lane = gid & 63;
    if (idx >= BATCH) return;
    int u  = users[idx];
    int pe = pos[idx];
    int ne = neg[idx];
    int pn = N_USERS + pe;
    int nn = N_USERS + ne;

    float s1p = 1.0f / (n0[u] * n0[pn]);
    float s1n = 1.0f / (n0[u] * n0[nn]);
    float s2p = 1.0f / (n1[u] * n1[pn]);
    float s2n = 1.0f / (n1[u] * n1[nn]);
    float s3p = 1.0f / (n2[u] * n2[pn]);
    float s3n = 1.0f / (n2[u] * n2[nn]);

    float ap = 0.f, an = 0.f;
    {
        float xu = ue[(size_t)u * 64 + lane];
        ap += xu * ee[(size_t)pe * 64 + lane];
        an += xu * ee[(size_t)ne * 64 + lane];
    }
    {
        float xu = e1[(size_t)u * 64 + lane];
        ap += xu * e1[(size_t)pn * 64 + lane] * s1p;
        an += xu * e1[(size_t)nn * 64 + lane] * s1n;
    }
    if (lane < 32) {
        float xu = bf2f(t2[(size_t)u * 32 + lane]);
        ap += xu * bf2f(t2[(size_t)pn * 32 + lane]) * s2p;
        an += xu * bf2f(t2[(size_t)nn * 32 + lane]) * s2n;
    } else if (lane < 48) {
        int d = lane - 32;
        float xu = bf2f(t3[(size_t)u * 16 + d]);
        ap += xu * bf2f(t3[(size_t)pn * 16 + d]) * s3p;
        an += xu * bf2f(t3[(size_t)nn * 16 + d]) * s3n;
    }
#pragma unroll
    for (int off = 32; off > 0; off >>= 1) {
        ap += __shfl_xor(ap, off);
        an += __shfl_xor(an, off);
    }
    if (lane == 0) {
        out[2 * idx + 0] = ap;
        out[2 * idx + 1] = an;
    }
}

// ===========================================================================
extern "C" void kernel_launch(void* const* d_in, const int* in_sizes, int n_in,
                              void* d_out, int out_size, void* d_ws, size_t ws_size,
                              hipStream_t stream) {
    const int*   users = (const int*)d_in[0];
    const int*   pos   = (const int*)d_in[1];
    const int*   neg   = (const int*)d_in[2];
    const int*   rows  = (const int*)d_in[3];
    const int*   cols  = (const int*)d_in[4];
    const float* vals  = (const float*)d_in[5];
    const float* ue    = (const float*)d_in[6];
    const float* ee    = (const float*)d_in[7];
    const float* Wg0 = (const float*)d_in[8],  *bg0 = (const float*)d_in[9];
    const float* Wb0 = (const float*)d_in[10], *bb0 = (const float*)d_in[11];
    const float* Wg1 = (const float*)d_in[12], *bg1 = (const float*)d_in[13];
    const float* Wb1 = (const float*)d_in[14], *bb1 = (const float*)d_in[15];
    const float* Wg2 = (const float*)d_in[16], *bg2 = (const float*)d_in[17];
    const float* Wb2 = (const float*)d_in[18], *bb2 = (const float*)d_in[19];

    // workspace (~128 MB; >=192 MB proven available)
    float* e1   = (float*)d_ws;                          // N x 64 fp32 (unnorm L1 out)
    float* n0   = e1 + (size_t)N_NODES * 64;             // N
    float* n1   = n0 + N_NODES;                          // N
    float* n2   = n1 + N_NODES;                          // N
    uint2* ep   = (uint2*)(n2 + N_NODES);                // E packed {col, val}
    unsigned short* tA = (unsigned short*)(ep + NE);     // N x 64 bf16 (t0, then t2)
    unsigned short* tB = tA + (size_t)N_NODES * 64;      // N x 64 bf16 (t1)
    unsigned short* t3 = tB + (size_t)N_NODES * 64;      // N x 16 bf16 (L3 out)
    unsigned short* wt = t3 + (size_t)N_NODES * 16;      // 13312 (transposed weights)
    int* deg  = (int*)(wt + 13312);                      // N
    int* rs   = deg + N_NODES;                           // N
    int* bcnt = rs + N_NODES;                            // NBUK
    int* bsc  = bcnt + NBUK;                             // NBUK + 1
    int* gcur = bsc + NBUK + 1;                          // NBUK
    uint2* part = (uint2*)e1;                            // E records (16 MB),
                                                         // reuses e1 (free until
                                                         // layer 0 writes it)

    // ---- CSR build via bucket sort + t0 table + weight transpose ----
    hipMemsetAsync(bcnt, 0, NBUK * sizeof(int), stream);
    bhist<<<PBLK, 256, 0, stream>>>((const int4*)rows, bcnt);
    bscan<<<1, 512, 0, stream>>>(bcnt, bsc, gcur);
    part_kernel<<<PBLK, 256, 0, stream>>>((const int4*)rows, (const int4*)cols,
                                          (const float4*)vals, gcur, part);
    bfill<<<NBUK, 512, 0, stream>>>(part, bsc, rs, deg, ep);
    init_misc<<<T0_BLKS + WT_BLKS, 256, 0, stream>>>(ue, ee, tA,
                                                     Wg0, Wb0, Wg1, Wb1, Wg2, Wb2, wt);

    // ---- 3 fused layers: gather -> LDS -> MFMA -> stores + norm ----
    layer_fused<64, 64, 0, 1><<<N_NODES / 16, 256, 0, stream>>>(
        rs, deg, ep, tA, ue, ee, nullptr, wt, wt + 4096, bg0, bb0, e1, tB, n0);
    layer_fused<64, 32, 1, 0><<<N_NODES / 32, 256, 0, stream>>>(
        rs, deg, ep, tB, ue, ee, e1, wt + 8192, wt + 10240, bg1, bb1, nullptr, tA, n1);
    layer_fused<32, 16, 2, 0><<<N_NODES / 64, 256, 0, stream>>>(
        rs, deg, ep, tA, ue, ee, nullptr, wt + 12288, wt + 12800, bg2, bb2, nullptr, t3, n2);

    // ---- scoring ----
    score_kernel<<<(BATCH * 64) / 256, 256, 0, stream>>>(users, pos, neg, ue, ee,
                                                         e1, n0, tA, n1, t3, n2,
                                                         (float*)d_out);
}

// Round 9
// 400.683 us; speedup vs baseline: 5.1398x; 1.1152x over previous
//
#include <hip/hip_runtime.h>

#define N_USERS 50000
#define N_ENT   150000
#define N_NODES 200000
#define NE      2000000
#define BATCH   8192

// bucket sort params: 512 rows per bucket
#define BSHIFT 9
#define BROWS  512
#define NBUK   391            // ceil(200000 / 512)
#define EPB    8192           // edges per block in hist/partition
#define PBLK   245            // ceil(NE / EPB)
#define T0_BLKS 12500         // N_NODES*64/4 / 256
#define WT_BLKS 52            // ceil(13312 / 256)

typedef __attribute__((ext_vector_type(8))) short   bf16x8;
typedef __attribute__((ext_vector_type(4))) float   f32x4;
typedef unsigned int u32;

__device__ __forceinline__ float bf2f(unsigned short b) {
    return __uint_as_float(((u32)b) << 16);
}
__device__ __forceinline__ float bflo(u32 x) {          // low bf16 of a pair
    return __uint_as_float(x << 16);
}
__device__ __forceinline__ float bfhi(u32 x) {          // high bf16 of a pair
    return __uint_as_float(x & 0xFFFF0000u);
}
__device__ __forceinline__ unsigned short f2bf(float f) {
    u32 u = __float_as_uint(f);
    u += 0x7FFF + ((u >> 16) & 1);          // round-to-nearest-even
    return (unsigned short)(u >> 16);
}
// pack 2 f32 -> 1 u32 of 2 bf16 (RNE), single instruction on gfx950.
// Verified numerically identical to f2bf pair in round 6 (same absmax).
__device__ __forceinline__ u32 cvtpk(float lo, float hi) {
    u32 r;
    asm("v_cvt_pk_bf16_f32 %0, %1, %2" : "=v"(r) : "v"(lo), "v"(hi));
    return r;
}

// ===========================================================================
// CSR build via 2-level bucket sort (r3-verified structure).
// LESSONS carried:
//  (r6) no per-edge LDS float atomics — DS-atomic latency serializes.
//  (r7) no indexed local arrays in the gather — scratch spill (1.58 GB wr).
//  (r8) record loads must be SCALAR (uniform addr) — per-lane broadcast
//       VMEM record loads doubled VMEM instr and cost +23 us/layer.
//  (r9) pad slots must read col=0 — otherwise they fetch the NEXT row's
//       random table lines (~38% wasted fabric traffic).
// ===========================================================================
__global__ __launch_bounds__(256) void bhist(const int4* __restrict__ rows4,
                                             int* __restrict__ bcnt) {
    __shared__ int lcnt[NBUK];
    for (int b = threadIdx.x; b < NBUK; b += 256) lcnt[b] = 0;
    __syncthreads();
    const int q0 = blockIdx.x * (EPB / 4);
#pragma unroll
    for (int k = 0; k < EPB / 1024; ++k) {
        int q = q0 + k * 256 + threadIdx.x;
        if (q < NE / 4) {
            int4 r = rows4[q];
            atomicAdd(&lcnt[r.x >> BSHIFT], 1);
            atomicAdd(&lcnt[r.y >> BSHIFT], 1);
            atomicAdd(&lcnt[r.z >> BSHIFT], 1);
            atomicAdd(&lcnt[r.w >> BSHIFT], 1);
        }
    }
    __syncthreads();
    for (int b = threadIdx.x; b < NBUK; b += 256) {
        int c = lcnt[b];
        if (c) atomicAdd(&bcnt[b], c);
    }
}

__global__ __launch_bounds__(512) void bscan(const int* __restrict__ bcnt,
                                             int* __restrict__ bsc,
                                             int* __restrict__ gcur) {
    __shared__ int buf[512];
    int t = threadIdx.x;
    int v = (t < NBUK) ? bcnt[t] : 0;
    buf[t] = v;
    __syncthreads();
    for (int off = 1; off < 512; off <<= 1) {
        int x = (t >= off) ? buf[t - off] : 0;
        __syncthreads();
        buf[t] += x;
        __syncthreads();
    }
    if (t < NBUK) {
        int excl = buf[t] - v;
        bsc[t]  = excl;
        gcur[t] = excl;
    }
    if (t == NBUK - 1) bsc[NBUK] = buf[t];   // == NE
}

// partition: records packed {(lrow<<18)|col, val_bits}; each block reserves
// one contiguous run per bucket -> coalesced-ish writes, no hot atomics.
__global__ __launch_bounds__(256) void part_kernel(const int4* __restrict__ rows4,
                                                   const int4* __restrict__ cols4,
                                                   const float4* __restrict__ vals4,
                                                   int* __restrict__ gcur,
                                                   uint2* __restrict__ part) {
    __shared__ int lcnt[NBUK];
    __shared__ int lbase[NBUK];
    for (int b = threadIdx.x; b < NBUK; b += 256) lcnt[b] = 0;
    __syncthreads();
    const int q0 = blockIdx.x * (EPB / 4);
    int4 rc[EPB / 1024];
#pragma unroll
    for (int k = 0; k < EPB / 1024; ++k) {
        int q = q0 + k * 256 + threadIdx.x;
        if (q < NE / 4) {
            int4 r = rows4[q];
            rc[k] = r;
            atomicAdd(&lcnt[r.x >> BSHIFT], 1);
            atomicAdd(&lcnt[r.y >> BSHIFT], 1);
            atomicAdd(&lcnt[r.z >> BSHIFT], 1);
            atomicAdd(&lcnt[r.w >> BSHIFT], 1);
        } else {
            rc[k] = make_int4(-1, -1, -1, -1);
        }
    }
    __syncthreads();
    for (int b = threadIdx.x; b < NBUK; b += 256) {
        int c = lcnt[b];
        lbase[b] = c ? atomicAdd(&gcur[b], c) : 0;
        lcnt[b] = 0;                       // reset for rank assignment
    }
    __syncthreads();
#pragma unroll
    for (int k = 0; k < EPB / 1024; ++k) {
        int q = q0 + k * 256 + threadIdx.x;
        if (q < NE / 4) {
            int4   c4 = cols4[q];
            float4 v4 = vals4[q];
            int r, b, rk;
            uint2 rec;
            r = rc[k].x; b = r >> BSHIFT; rk = atomicAdd(&lcnt[b], 1);
            rec.x = ((u32)(r & (BROWS - 1)) << 18) | (u32)c4.x;
            rec.y = __float_as_uint(v4.x);  part[lbase[b] + rk] = rec;
            r = rc[k].y; b = r >> BSHIFT; rk = atomicAdd(&lcnt[b], 1);
            rec.x = ((u32)(r & (BROWS - 1)) << 18) | (u32)c4.y;
            rec.y = __float_as_uint(v4.y);  part[lbase[b] + rk] = rec;
            r = rc[k].z; b = r >> BSHIFT; rk = atomicAdd(&lcnt[b], 1);
            rec.x = ((u32)(r & (BROWS - 1)) << 18) | (u32)c4.z;
            rec.y = __float_as_uint(v4.z);  part[lbase[b] + rk] = rec;
            r = rc[k].w; b = r >> BSHIFT; rk = atomicAdd(&lcnt[b], 1);
            rec.x = ((u32)(r & (BROWS - 1)) << 18) | (u32)c4.w;
            rec.y = __float_as_uint(v4.w);  part[lbase[b] + rk] = rec;
        }
    }
}

// one block per bucket: row-hist -> LDS scan -> rs/deg, then LDS-cursor fill
__global__ __launch_bounds__(512) void bfill(const uint2* __restrict__ part,
                                             const int* __restrict__ bsc,
                                             int* __restrict__ rs,
                                             int* __restrict__ deg,
                                             uint2* __restrict__ ep) {
    __shared__ int h[BROWS];
    __shared__ int sc[BROWS];
    const int b = blockIdx.x;
    const int t = threadIdx.x;
    const int s = bsc[b];
    const int e = bsc[b + 1];
    h[t] = 0;
    __syncthreads();
    for (int i = s + t; i < e; i += 512)
        atomicAdd(&h[part[i].x >> 18], 1);
    __syncthreads();
    int v = h[t];
    sc[t] = v;
    __syncthreads();
    for (int off = 1; off < 512; off <<= 1) {
        int x = (t >= off) ? sc[t - off] : 0;
        __syncthreads();
        sc[t] += x;
        __syncthreads();
    }
    const int row = b * BROWS + t;
    if (row < N_NODES) {
        deg[row] = v;
        rs[row]  = s + sc[t];              // row_end convention
    }
    h[t] = s + sc[t] - v;                  // cursor = row_start
    __syncthreads();
    for (int i = s + t; i < e; i += 512) {
        uint2 rec = part[i];
        int lr  = rec.x >> 18;
        int pos = atomicAdd(&h[lr], 1);
        uint2 o;
        o.x = rec.x & 0x3FFFF;
        o.y = rec.y;
        ep[pos] = o;                       // bucket slice ~40 KB -> L2-local
    }
}

// ---------------------------------------------------------------------------
// init_misc = build_t0 (blocks 0..12499) + weight transpose (blocks 12500+).
// t0 = bf16(concat(ue,ee)); wt layout (ushort): wg0T@0 wb0T@4096 wg1T@8192
// wb1T@10240 wg2T@12288 wb2T@12800 (total 13312), all [n][k] k-contiguous.
// ---------------------------------------------------------------------------
__global__ __launch_bounds__(256) void init_misc(
        const float* __restrict__ ue, const float* __restrict__ ee,
        unsigned short* __restrict__ t0,
        const float* __restrict__ Wg0, const float* __restrict__ Wb0,
        const float* __restrict__ Wg1, const float* __restrict__ Wb1,
        const float* __restrict__ Wg2, const float* __restrict__ Wb2,
        unsigned short* __restrict__ wt) {
    if (blockIdx.x < T0_BLKS) {
        int i = blockIdx.x * 256 + threadIdx.x;          // float4 index
        const int uelems = N_USERS * 64 / 4;
        float4 v = (i < uelems) ? ((const float4*)ue)[i]
                                : ((const float4*)ee)[i - uelems];
        ushort4 o;
        o.x = f2bf(v.x); o.y = f2bf(v.y); o.z = f2bf(v.z); o.w = f2bf(v.w);
        ((ushort4*)t0)[i] = o;
        return;
    }
    int idx = (blockIdx.x - T0_BLKS) * 256 + threadIdx.x;
    if (idx < 4096) {                       // Wg0: 64x64
        int k = idx >> 6, n = idx & 63;
        wt[0 + n * 64 + k] = f2bf(Wg0[idx]);
    } else if (idx < 8192) {                // Wb0: 64x64
        int r = idx - 4096; int k = r >> 6, n = r & 63;
        wt[4096 + n * 64 + k] = f2bf(Wb0[r]);
    } else if (idx < 10240) {               // Wg1: 64x32
        int r = idx - 8192; int k = r >> 5, n = r & 31;
        wt[8192 + n * 64 + k] = f2bf(Wg1[r]);
    } else if (idx < 12288) {               // Wb1: 64x32
        int r = idx - 10240; int k = r >> 5, n = r & 31;
        wt[10240 + n * 64 + k] = f2bf(Wb1[r]);
    } else if (idx < 12800) {               // Wg2: 32x16
        int r = idx - 12288; int k = r >> 4, n = r & 15;
        wt[12288 + n * 32 + k] = f2bf(Wg2[r]);
    } else if (idx < 13312) {               // Wb2: 32x16
        int r = idx - 12800; int k = r >> 4, n = r & 15;
        wt[12800 + n * 32 + k] = f2bf(Wb2[r]);
    }
}

// ===========================================================================
// Fused layer (r9 = r5 structure + pad-masking + 16-edge named-scalar
// unroll + cvtpk). Gather: wave-per-row; records loaded SCALAR (uniform
// addr, r8 lesson); pad slots (k >= rem, uniform) masked to col=0/val=0 so
// they hit the cache-hot line 0 instead of fetching the next row's random
// lines (r9 lesson: ~38% of fetches were waste). 8 table lines in flight
// (DIN=64). NAMED SCALARS ONLY (r7 lesson).
// EGO: 0 = ue/ee fp32 (L0), 1 = xin fp32 (L1), 2 = tin bf16 (L2).
// mfma_f32_16x16x32_bf16: A[row=l&15][k=(l>>4)*8+j], B[k][col=l&15],
// D col=l&15, row=(l>>4)*4+reg  (layout verified rounds 1-6).
// ===========================================================================
template <int DIN, int DOUT, int EGO, int WX>
__global__ __launch_bounds__(256) void layer_fused(
        const int* __restrict__ rs, const int* __restrict__ deg,
        const uint2* __restrict__ ep,
        const unsigned short* __restrict__ tin,
        const float* __restrict__ ue, const float* __restrict__ ee,
        const float* __restrict__ xin,
        const unsigned short* __restrict__ WgT,   // bf16 [DOUT][DIN]
        const unsigned short* __restrict__ WbT,
        const float* __restrict__ bg, const float* __restrict__ bb,
        float* __restrict__ xout,                 // fp32 [N][DOUT] (if WX)
        unsigned short* __restrict__ tout,        // bf16 [N][DOUT]
        float* __restrict__ norm_out) {
    constexpr int NTC = DOUT / 16;        // col tiles per block
    constexpr int R   = (4 / NTC) * 16;   // rows per block
    constexpr int RPW = R / 4;            // rows gathered per wave
    constexpr int KS  = DIN / 32;

    __shared__ __align__(16) unsigned short sH[R * DIN];
    __shared__ __align__(16) unsigned short sP[R * DIN];
    __shared__ float sPart[R * NTC];

    const int lane    = threadIdx.x & 63;
    const int wave    = threadIdx.x >> 6;
    const int rowbase = blockIdx.x * R;

    // ---- gather phase: wave gathers its RPW rows sequentially ----
    for (int rr = 0; rr < RPW; ++rr) {
        const int lr  = wave * RPW + rr;
        const int row = __builtin_amdgcn_readfirstlane(rowbase + lr);
        const int end   = rs[row];
        const int start = end - deg[row];

        if (DIN == 64) {
            const int g  = lane >> 5;          // half-wave: edge sub-slot
            const int d2 = lane & 31;          // bf16-pair index
            const u32* t32 = (const u32*)tin;
            float ax0 = 0.f, ax1 = 0.f, ax2 = 0.f, ax3 = 0.f;
            float ay0 = 0.f, ay1 = 0.f, ay2 = 0.f, ay3 = 0.f;
            for (int i = start; i < end; i += 16) {
                const int rem = end - i;               // uniform
                // 16 scalar record loads (uniform addrs -> s_load)
                uint2 q0  = ep[i + 0],  q1  = ep[i + 1];
                uint2 q2  = ep[i + 2],  q3  = ep[i + 3];
                uint2 q4  = ep[i + 4],  q5  = ep[i + 5];
                uint2 q6  = ep[i + 6],  q7  = ep[i + 7];
                uint2 q8  = ep[i + 8],  q9  = ep[i + 9];
                uint2 q10 = ep[i + 10], q11 = ep[i + 11];
                uint2 q12 = ep[i + 12], q13 = ep[i + 13];
                uint2 q14 = ep[i + 14], q15 = ep[i + 15];
                // uniform pad-masking (scalar cselect): pad -> col 0, val 0
                u32 m0  = (0  < rem) ? q0.x  : 0u;  u32 w0  = (0  < rem) ? q0.y  : 0u;
                u32 m1  = (1  < rem) ? q1.x  : 0u;  u32 w1  = (1  < rem) ? q1.y  : 0u;
                u32 m2  = (2  < rem) ? q2.x  : 0u;  u32 w2  = (2  < rem) ? q2.y  : 0u;
                u32 m3  = (3  < rem) ? q3.x  : 0u;  u32 w3  = (3  < rem) ? q3.y  : 0u;
                u32 m4  = (4  < rem) ? q4.x  : 0u;  u32 w4  = (4  < rem) ? q4.y  : 0u;
                u32 m5  = (5  < rem) ? q5.x  : 0u;  u32 w5  = (5  < rem) ? q5.y  : 0u;
                u32 m6  = (6  < rem) ? q6.x  : 0u;  u32 w6  = (6  < rem) ? q6.y  : 0u;
                u32 m7  = (7  < rem) ? q7.x  : 0u;  u32 w7  = (7  < rem) ? q7.y  : 0u;
                u32 m8  = (8  < rem) ? q8.x  : 0u;  u32 w8  = (8  < rem) ? q8.y  : 0u;
                u32 m9  = (9  < rem) ? q9.x  : 0u;  u32 w9  = (9  < rem) ? q9.y  : 0u;
                u32 m10 = (10 < rem) ? q10.x : 0u;  u32 w10 = (10 < rem) ? q10.y : 0u;
                u32 m11 = (11 < rem) ? q11.x : 0u;  u32 w11 = (11 < rem) ? q11.y : 0u;
                u32 m12 = (12 < rem) ? q12.x : 0u;  u32 w12 = (12 < rem) ? q12.y : 0u;
                u32 m13 = (13 < rem) ? q13.x : 0u;  u32 w13 = (13 < rem) ? q13.y : 0u;
                u32 m14 = (14 < rem) ? q14.x : 0u;  u32 w14 = (14 < rem) ? q14.y : 0u;
                u32 m15 = (15 < rem) ? q15.x : 0u;  u32 w15 = (15 < rem) ? q15.y : 0u;
                // half-wave slot selects (1 cndmask each)
                u32 s0 = g ? m1  : m0;   float v0 = __uint_as_float(g ? w1  : w0);
                u32 s1 = g ? m3  : m2;   float v1 = __uint_as_float(g ? w3  : w2);
                u32 s2 = g ? m5  : m4;   float v2 = __uint_as_float(g ? w5  : w4);
                u32 s3 = g ? m7  : m6;   float v3 = __uint_as_float(g ? w7  : w6);
                u32 s4 = g ? m9  : m8;   float v4 = __uint_as_float(g ? w9  : w8);
                u32 s5 = g ? m11 : m10;  float v5 = __uint_as_float(g ? w11 : w10);
                u32 s6 = g ? m13 : m12;  float v6 = __uint_as_float(g ? w13 : w12);
                u32 s7 = g ? m15 : m14;  float v7 = __uint_as_float(g ? w15 : w14);
                // 8 table lines in flight
                u32 x0 = t32[(size_t)s0 * 32 + d2];
                u32 x1 = t32[(size_t)s1 * 32 + d2];
                u32 x2 = t32[(size_t)s2 * 32 + d2];
                u32 x3 = t32[(size_t)s3 * 32 + d2];
                u32 x4 = t32[(size_t)s4 * 32 + d2];
                u32 x5 = t32[(size_t)s5 * 32 + d2];
                u32 x6 = t32[(size_t)s6 * 32 + d2];
                u32 x7 = t32[(size_t)s7 * 32 + d2];
                ax0 = fmaf(v0, bflo(x0), ax0);  ay0 = fmaf(v0, bfhi(x0), ay0);
                ax1 = fmaf(v1, bflo(x1), ax1);  ay1 = fmaf(v1, bfhi(x1), ay1);
                ax2 = fmaf(v2, bflo(x2), ax2);  ay2 = fmaf(v2, bfhi(x2), ay2);
                ax3 = fmaf(v3, bflo(x3), ax3);  ay3 = fmaf(v3, bfhi(x3), ay3);
                ax0 = fmaf(v4, bflo(x4), ax0);  ay0 = fmaf(v4, bfhi(x4), ay0);
                ax1 = fmaf(v5, bflo(x5), ax1);  ay1 = fmaf(v5, bfhi(x5), ay1);
                ax2 = fmaf(v6, bflo(x6), ax2);  ay2 = fmaf(v6, bfhi(x6), ay2);
                ax3 = fmaf(v7, bflo(x7), ax3);  ay3 = fmaf(v7, bfhi(x7), ay3);
            }
            float ax = (ax0 + ax1) + (ax2 + ax3);
            float ay = (ay0 + ay1) + (ay2 + ay3);
            ax += __shfl_xor(ax, 32);
            ay += __shfl_xor(ay, 32);

            float ex, ey;
            if (EGO == 0) {
                const float2* src = (row < N_USERS)
                    ? (const float2*)ue + (size_t)row * 32
                    : (const float2*)ee + (size_t)(row - N_USERS) * 32;
                float2 ev = src[d2];  ex = ev.x;  ey = ev.y;
            } else if (EGO == 1) {
                float2 ev = ((const float2*)xin)[(size_t)row * 32 + d2];
                ex = ev.x;  ey = ev.y;
            } else {
                u32 tv = t32[(size_t)row * 32 + d2];
                ex = bflo(tv);  ey = bfhi(tv);
            }
            if (g == 0) {
                ((u32*)sH)[lr * 32 + d2] = cvtpk(ex + ax, ey + ay);
                ((u32*)sP)[lr * 32 + d2] = cvtpk(ex * ax, ey * ay);
            }
        } else {   // DIN == 32: quarter-waves, 16 edges/iter, 4 lines in flight
            const int g  = lane >> 4;          // 0..3
            const int d2 = lane & 15;
            const u32* t16 = (const u32*)tin;
            float ax0 = 0.f, ax1 = 0.f;
            float ay0 = 0.f, ay1 = 0.f;
            for (int i = start; i < end; i += 16) {
                const int rem = end - i;
                uint2 q0  = ep[i + 0],  q1  = ep[i + 1];
                uint2 q2  = ep[i + 2],  q3  = ep[i + 3];
                uint2 q4  = ep[i + 4],  q5  = ep[i + 5];
                uint2 q6  = ep[i + 6],  q7  = ep[i + 7];
                uint2 q8  = ep[i + 8],  q9  = ep[i + 9];
                uint2 q10 = ep[i + 10], q11 = ep[i + 11];
                uint2 q12 = ep[i + 12], q13 = ep[i + 13];
                uint2 q14 = ep[i + 14], q15 = ep[i + 15];
                u32 m0  = (0  < rem) ? q0.x  : 0u;  u32 w0  = (0  < rem) ? q0.y  : 0u;
                u32 m1  = (1  < rem) ? q1.x  : 0u;  u32 w1  = (1  < rem) ? q1.y  : 0u;
                u32 m2  = (2  < rem) ? q2.x  : 0u;  u32 w2  = (2  < rem) ? q2.y  : 0u;
                u32 m3  = (3  < rem) ? q3.x  : 0u;  u32 w3  = (3  < rem) ? q3.y  : 0u;
                u32 m4  = (4  < rem) ? q4.x  : 0u;  u32 w4  = (4  < rem) ? q4.y  : 0u;
                u32 m5  = (5  < rem) ? q5.x  : 0u;  u32 w5  = (5  < rem) ? q5.y  : 0u;
                u32 m6  = (6  < rem) ? q6.x  : 0u;  u32 w6  = (6  < rem) ? q6.y  : 0u;
                u32 m7  = (7  < rem) ? q7.x  : 0u;  u32 w7  = (7  < rem) ? q7.y  : 0u;
                u32 m8  = (8  < rem) ? q8.x  : 0u;  u32 w8  = (8  < rem) ? q8.y  : 0u;
                u32 m9  = (9  < rem) ? q9.x  : 0u;  u32 w9  = (9  < rem) ? q9.y  : 0u;
                u32 m10 = (10 < rem) ? q10.x : 0u;  u32 w10 = (10 < rem) ? q10.y : 0u;
                u32 m11 = (11 < rem) ? q11.x : 0u;  u32 w11 = (11 < rem) ? q11.y : 0u;
                u32 m12 = (12 < rem) ? q12.x : 0u;  u32 w12 = (12 < rem) ? q12.y : 0u;
                u32 m13 = (13 < rem) ? q13.x : 0u;  u32 w13 = (13 < rem) ? q13.y : 0u;
                u32 m14 = (14 < rem) ? q14.x : 0u;  u32 w14 = (14 < rem) ? q14.y : 0u;
                u32 m15 = (15 < rem) ? q15.x : 0u;  u32 w15 = (15 < rem) ? q15.y : 0u;
                // quarter-wave slot selects: slot k covers edges 4k+g
                u32 ta, tb; float fa, fb;
                ta = (g & 1) ? m1  : m0;   tb = (g & 1) ? m3  : m2;
                fa = __uint_as_float((g & 1) ? w1  : w0);
                fb = __uint_as_float((g & 1) ? w3  : w2);
                u32 s0 = (g & 2) ? tb : ta;  float v0 = (g & 2) ? fb : fa;
                ta = (g & 1) ? m5  : m4;   tb = (g & 1) ? m7  : m6;
                fa = __uint_as_float((g & 1) ? w5  : w4);
                fb = __uint_as_float((g & 1) ? w7  : w6);
                u32 s1 = (g & 2) ? tb : ta;  float v1 = (g & 2) ? fb : fa;
                ta = (g & 1) ? m9  : m8;   tb = (g & 1) ? m11 : m10;
                fa = __uint_as_float((g & 1) ? w9  : w8);
                fb = __uint_as_float((g & 1) ? w11 : w10);
                u32 s2 = (g & 2) ? tb : ta;  float v2 = (g & 2) ? fb : fa;
                ta = (g & 1) ? m13 : m12;  tb = (g & 1) ? m15 : m14;
                fa = __uint_as_float((g & 1) ? w13 : w12);
                fb = __uint_as_float((g & 1) ? w15 : w14);
                u32 s3 = (g & 2) ? tb : ta;  float v3 = (g & 2) ? fb : fa;
                u32 x0 = t16[(size_t)s0 * 16 + d2];
                u32 x1 = t16[(size_t)s1 * 16 + d2];
                u32 x2 = t16[(size_t)s2 * 16 + d2];
                u32 x3 = t16[(size_t)s3 * 16 + d2];
                ax0 = fmaf(v0, bflo(x0), ax0);  ay0 = fmaf(v0, bfhi(x0), ay0);
                ax1 = fmaf(v1, bflo(x1), ax1);  ay1 = fmaf(v1, bfhi(x1), ay1);
                ax0 = fmaf(v2, bflo(x2), ax0);  ay0 = fmaf(v2, bfhi(x2), ay0);
                ax1 = fmaf(v3, bflo(x3), ax1);  ay1 = fmaf(v3, bfhi(x3), ay1);
            }
            float ax = ax0 + ax1;
            float ay = ay0 + ay1;
            ax += __shfl_xor(ax, 32);  ay += __shfl_xor(ay, 32);
            ax += __shfl_xor(ax, 16);  ay += __shfl_xor(ay, 16);

            float ex, ey;
            if (EGO == 2) {
                u32 tv = t16[(size_t)row * 16 + d2];
                ex = bflo(tv);  ey = bfhi(tv);
            } else if (EGO == 1) {
                float2 ev = ((const float2*)xin)[(size_t)row * 16 + d2];
                ex = ev.x;  ey = ev.y;
            } else {
                const float2* src = (row < N_USERS)
                    ? (const float2*)ue + (size_t)row * 32
                    : (const float2*)ee + (size_t)(row - N_USERS) * 32;
                float2 ev = src[d2];  ex = ev.x;  ey = ev.y;
            }
            if (g == 0) {
                ((u32*)sH)[lr * 16 + d2] = cvtpk(ex + ax, ey + ay);
                ((u32*)sP)[lr * 16 + d2] = cvtpk(ex * ax, ey * ay);
            }
        }
    }
    __syncthreads();

    // ---- MFMA phase: wave (rt, ct) computes 16 rows x 16 cols ----
    const int ct  = wave % NTC;
    const int rt  = wave / NTC;
    const int r16 = lane & 15;
    const int g4  = lane >> 4;

    bf16x8 ah[KS], ap[KS];
#pragma unroll
    for (int s = 0; s < KS; ++s) {
        const int aoff = (rt * 16 + r16) * DIN + g4 * 8 + s * 32;
        ah[s] = *reinterpret_cast<const bf16x8*>(sH + aoff);
        ap[s] = *reinterpret_cast<const bf16x8*>(sP + aoff);
    }
    f32x4 accg = (f32x4){0.f, 0.f, 0.f, 0.f};
    f32x4 accb = (f32x4){0.f, 0.f, 0.f, 0.f};
#pragma unroll
    for (int s = 0; s < KS; ++s) {
        const int boff = (ct * 16 + r16) * DIN + g4 * 8 + s * 32;
        bf16x8 bgf = *reinterpret_cast<const bf16x8*>(WgT + boff);
        bf16x8 bbf = *reinterpret_cast<const bf16x8*>(WbT + boff);
        accg = __builtin_amdgcn_mfma_f32_16x16x32_bf16(ah[s], bgf, accg, 0, 0, 0);
        accb = __builtin_amdgcn_mfma_f32_16x16x32_bf16(ap[s], bbf, accb, 0, 0, 0);
    }

    // epilogue: bias + leaky + sum, stores, per-row norm partials
    const int col = ct * 16 + r16;
    const float bgv = bg[col];
    const float bbv = bb[col];
    float ss[4];
#pragma unroll
    for (int r = 0; r < 4; ++r) {
        float a = accg[r] + bgv; a = a > 0.f ? a : 0.01f * a;
        float b = accb[r] + bbv; b = b > 0.f ? b : 0.01f * b;
        float nv = a + b;
        const int row = rowbase + rt * 16 + g4 * 4 + r;
        if (WX) xout[(size_t)row * DOUT + col] = nv;
        tout[(size_t)row * DOUT + col] = f2bf(nv);
        ss[r] = nv * nv;
    }
#pragma unroll
    for (int off = 1; off < 16; off <<= 1) {
#pragma unroll
        for (int r = 0; r < 4; ++r) ss[r] += __shfl_xor(ss[r], off);
    }
    if (r16 == 0) {
#pragma unroll
        for (int r = 0; r < 4; ++r)
            sPart[(rt * 16 + g4 * 4 + r) * NTC + ct] = ss[r];
    }
    __syncthreads();
    for (int t = threadIdx.x; t < R; t += 256) {
        float s = 0.f;
#pragma unroll
        for (int j = 0; j < NTC; ++j) s += sPart[t * NTC + j];
        norm_out[rowbase + t] = fmaxf(sqrtf(s), 1e-12f);
    }
}

// ===========================================================================
// Scoring: one wave per batch element; sections 64 raw + 64 (e1 fp32) +
// 32 (t2 bf16) + 16 (t3 bf16); normalization folded as 1/(norm products).
// ===========================================================================
__global__ __launch_bounds__(256) void score_kernel(
        const int* __restrict__ users, const int* __restrict__ pos,
        const int* __restrict__ neg,
        const float* __restrict__ ue, const float* __restrict__ ee,
        const float* __restrict__ e1, const float* __restrict__ n0,
        const unsigned short* __restrict__ t2, const float* __restrict__ n1,
        const unsigned short* __restrict__ t3, const float* __restrict__ n2,
        float* __restrict__ out) {
    int gid  = blockIdx.x * 256 + threadIdx.x;
    int idx  = gid >> 6;
    int lane = gid & 63;
    if (idx >= BATCH) return;
    int u  = users[idx];
    int pe = pos[idx];
    int ne = neg[idx];
    int pn = N_USERS + pe;
    int nn = N_USERS + ne;

    float s1p = 1.0f / (n0[u] * n0[pn]);
    float s1n = 1.0f / (n0[u] * n0[nn]);
    float s2p = 1.0f / (n1[u] * n1[pn]);
    float s2n = 1.0f / (n1[u] * n1[nn]);
    float s3p = 1.0f / (n2[u] * n2[pn]);
    float s3n = 1.0f / (n2[u] * n2[nn]);

    float ap = 0.f, an = 0.f;
    {
        float xu = ue[(size_t)u * 64 + lane];
        ap += xu * ee[(size_t)pe * 64 + lane];
        an += xu * ee[(size_t)ne * 64 + lane];
    }
    {
        float xu = e1[(size_t)u * 64 + lane];
        ap += xu * e1[(size_t)pn * 64 + lane] * s1p;
        an += xu * e1[(size_t)nn * 64 + lane] * s1n;
    }
    if (lane < 32) {
        float xu = bf2f(t2[(size_t)u * 32 + lane]);
        ap += xu * bf2f(t2[(size_t)pn * 32 + lane]) * s2p;
        an += xu * bf2f(t2[(size_t)nn * 32 + lane]) * s2n;
    } else if (lane < 48) {
        int d = lane - 32;
        float xu = bf2f(t3[(size_t)u * 16 + d]);
        ap += xu * bf2f(t3[(size_t)pn * 16 + d]) * s3p;
        an += xu * bf2f(t3[(size_t)nn * 16 + d]) * s3n;
    }
#pragma unroll
    for (int off = 32; off > 0; off >>= 1) {
        ap += __shfl_xor(ap, off);
        an += __shfl_xor(an, off);
    }
    if (lane == 0) {
        out[2 * idx + 0] = ap;
        out[2 * idx + 1] = an;
    }
}

// ===========================================================================
extern "C" void kernel_launch(void* const* d_in, const int* in_sizes, int n_in,
                              void* d_out, int out_size, void* d_ws, size_t ws_size,
                              hipStream_t stream) {
    const int*   users = (const int*)d_in[0];
    const int*   pos   = (const int*)d_in[1];
    const int*   neg   = (const int*)d_in[2];
    const int*   rows  = (const int*)d_in[3];
    const int*   cols  = (const int*)d_in[4];
    const float* vals  = (const float*)d_in[5];
    const float* ue    = (const float*)d_in[6];
    const float* ee    = (const float*)d_in[7];
    const float* Wg0 = (const float*)d_in[8],  *bg0 = (const float*)d_in[9];
    const float* Wb0 = (const float*)d_in[10], *bb0 = (const float*)d_in[11];
    const float* Wg1 = (const float*)d_in[12], *bg1 = (const float*)d_in[13];
    const float* Wb1 = (const float*)d_in[14], *bb1 = (const float*)d_in[15];
    const float* Wg2 = (const float*)d_in[16], *bg2 = (const float*)d_in[17];
    const float* Wb2 = (const float*)d_in[18], *bb2 = (const float*)d_in[19];

    // workspace (~128 MB; >=192 MB proven available)
    float* e1   = (float*)d_ws;                          // N x 64 fp32 (unnorm L1 out)
    float* n0   = e1 + (size_t)N_NODES * 64;             // N
    float* n1   = n0 + N_NODES;                          // N
    float* n2   = n1 + N_NODES;                          // N
    uint2* ep   = (uint2*)(n2 + N_NODES);                // E packed {col, val}
    unsigned short* tA = (unsigned short*)(ep + NE);     // N x 64 bf16 (t0, then t2)
    unsigned short* tB = tA + (size_t)N_NODES * 64;      // N x 64 bf16 (t1)
    unsigned short* t3 = tB + (size_t)N_NODES * 64;      // N x 16 bf16 (L3 out)
    unsigned short* wt = t3 + (size_t)N_NODES * 16;      // 13312 (transposed weights)
    int* deg  = (int*)(wt + 13312);                      // N
    int* rs   = deg + N_NODES;                           // N
    int* bcnt = rs + N_NODES;                            // NBUK
    int* bsc  = bcnt + NBUK;                             // NBUK + 1
    int* gcur = bsc + NBUK + 1;                          // NBUK
    uint2* part = (uint2*)e1;                            // E records (16 MB),
                                                         // reuses e1 (free until
                                                         // layer 0 writes it)

    // ---- CSR build via bucket sort + t0 table + weight transpose ----
    hipMemsetAsync(bcnt, 0, NBUK * sizeof(int), stream);
    bhist<<<PBLK, 256, 0, stream>>>((const int4*)rows, bcnt);
    bscan<<<1, 512, 0, stream>>>(bcnt, bsc, gcur);
    part_kernel<<<PBLK, 256, 0, stream>>>((const int4*)rows, (const int4*)cols,
                                          (const float4*)vals, gcur, part);
    bfill<<<NBUK, 512, 0, stream>>>(part, bsc, rs, deg, ep);
    init_misc<<<T0_BLKS + WT_BLKS, 256, 0, stream>>>(ue, ee, tA,
                                                     Wg0, Wb0, Wg1, Wb1, Wg2, Wb2, wt);

    // ---- 3 fused layers: gather -> LDS -> MFMA -> stores + norm ----
    layer_fused<64, 64, 0, 1><<<N_NODES / 16, 256, 0, stream>>>(
        rs, deg, ep, tA, ue, ee, nullptr, wt, wt + 4096, bg0, bb0, e1, tB, n0);
    layer_fused<64, 32, 1, 0><<<N_NODES / 32, 256, 0, stream>>>(
        rs, deg, ep, tB, ue, ee, e1, wt + 8192, wt + 10240, bg1, bb1, nullptr, tA, n1);
    layer_fused<32, 16, 2, 0><<<N_NODES / 64, 256, 0, stream>>>(
        rs, deg, ep, tA, ue, ee, nullptr, wt + 12288, wt + 12800, bg2, bb2, nullptr, t3, n2);

    // ---- scoring ----
    score_kernel<<<(BATCH * 64) / 256, 256, 0, stream>>>(users, pos, neg, ue, ee,
                                                         e1, n0, tA, n1, t3, n2,
                                                         (float*)d_out);
}

// Round 12
// 393.594 us; speedup vs baseline: 5.2324x; 1.0180x over previous
//
#include <hip/hip_runtime.h>

#define N_USERS 50000
#define N_ENT   150000
#define N_NODES 200000
#define NE      2000000
#define BATCH   8192

// bucket sort params: 512 rows per bucket
#define BSHIFT 9
#define BROWS  512
#define NBUK   391            // ceil(200000 / 512)
#define EPB    8192           // edges per block in hist/partition
#define PBLK   245            // ceil(NE / EPB)
#define T0_BLKS 12500         // N_NODES*64/4 / 256
#define WT_BLKS 52            // ceil(13312 / 256)

typedef __attribute__((ext_vector_type(8))) _Float16 f16x8;
typedef __attribute__((ext_vector_type(4))) float    f32x4;
typedef unsigned int u32;

// ---- fp16 helpers (r10: tables switched bf16 -> fp16 so the gather's
// unpack+fma folds into v_fma_mix_f32; fp16 has MORE mantissa bits than
// bf16 -> numerics improve; all values << fp16 range) ----
__device__ __forceinline__ float hlo(u32 x) {           // low fp16 of a pair
    union { unsigned short s; _Float16 h; } c;
    c.s = (unsigned short)x;
    return (float)c.h;
}
__device__ __forceinline__ float hhi(u32 x) {           // high fp16 of a pair
    union { unsigned short s; _Float16 h; } c;
    c.s = (unsigned short)(x >> 16);
    return (float)c.h;
}
__device__ __forceinline__ float h2f(unsigned short s) {
    union { unsigned short s; _Float16 h; } c;
    c.s = s;
    return (float)c.h;
}
__device__ __forceinline__ unsigned short f2h(float f) { // RNE
    union { _Float16 h; unsigned short s; } c;
    c.h = (_Float16)f;
    return c.s;
}
// pack 2 f32 -> 2 fp16 in one u32, single instr (v_cvt_pkrtz_f16_f32).
// Inline asm (r11 fix: the builtin returns __fp16x2 which clang won't
// assign across to _Float16x2). RTZ rounding: <=1 ulp fp16 on H/P
// intermediates, still 4x tighter than the bf16 path that passed r1-r9.
__device__ __forceinline__ u32 pkh(float lo, float hi) {
    u32 r;
    asm("v_cvt_pkrtz_f16_f32 %0, %1, %2" : "=v"(r) : "v"(lo), "v"(hi));
    return r;
}

// ===========================================================================
// CSR build via 2-level bucket sort (r3-verified structure).
// LESSONS carried:
//  (r6) no per-edge LDS float atomics — DS-atomic latency serializes.
//  (r7) no indexed local arrays in the gather — scratch spill (1.58 GB wr).
//  (r8) record loads must be SCALAR (uniform addr) — per-lane broadcast
//       VMEM record loads doubled VMEM instr and cost +23 us/layer.
//  (r9) pad slots masked to col=0 (cache-hot line), deep named-scalar unroll.
// bhist doubles as init kernel (blocks >= PBLK build t0 + transpose weights)
// — overlaps the independent init work with the histogram.
// ===========================================================================
__global__ __launch_bounds__(256) void bhist(const int4* __restrict__ rows4,
                                             int* __restrict__ bcnt,
                                             const float* __restrict__ ue,
                                             const float* __restrict__ ee,
                                             unsigned short* __restrict__ t0,
                                             const float* __restrict__ Wg0,
                                             const float* __restrict__ Wb0,
                                             const float* __restrict__ Wg1,
                                             const float* __restrict__ Wb1,
                                             const float* __restrict__ Wg2,
                                             const float* __restrict__ Wb2,
                                             unsigned short* __restrict__ wt) {
    if (blockIdx.x >= PBLK) {               // ---- init part ----
        int bi = blockIdx.x - PBLK;
        if (bi < T0_BLKS) {                 // t0 = fp16(concat(ue, ee))
            int i = bi * 256 + threadIdx.x; // float4 index
            const int uelems = N_USERS * 64 / 4;
            float4 v = (i < uelems) ? ((const float4*)ue)[i]
                                    : ((const float4*)ee)[i - uelems];
            ushort4 o;
            o.x = f2h(v.x); o.y = f2h(v.y); o.z = f2h(v.z); o.w = f2h(v.w);
            ((ushort4*)t0)[i] = o;
            return;
        }
        // weight transpose -> fp16 [n][k]; layout (ushort): wg0T@0 wb0T@4096
        // wg1T@8192 wb1T@10240 wg2T@12288 wb2T@12800 (total 13312)
        int idx = (bi - T0_BLKS) * 256 + threadIdx.x;
        if (idx < 4096) {                       // Wg0: 64x64
            int k = idx >> 6, n = idx & 63;
            wt[0 + n * 64 + k] = f2h(Wg0[idx]);
        } else if (idx < 8192) {                // Wb0: 64x64
            int r = idx - 4096; int k = r >> 6, n = r & 63;
            wt[4096 + n * 64 + k] = f2h(Wb0[r]);
        } else if (idx < 10240) {               // Wg1: 64x32
            int r = idx - 8192; int k = r >> 5, n = r & 31;
            wt[8192 + n * 64 + k] = f2h(Wg1[r]);
        } else if (idx < 12288) {               // Wb1: 64x32
            int r = idx - 10240; int k = r >> 5, n = r & 31;
            wt[10240 + n * 64 + k] = f2h(Wb1[r]);
        } else if (idx < 12800) {               // Wg2: 32x16
            int r = idx - 12288; int k = r >> 4, n = r & 15;
            wt[12288 + n * 32 + k] = f2h(Wg2[r]);
        } else if (idx < 13312) {               // Wb2: 32x16
            int r = idx - 12800; int k = r >> 4, n = r & 15;
            wt[12800 + n * 32 + k] = f2h(Wb2[r]);
        }
        return;
    }
    // ---- histogram part ----
    __shared__ int lcnt[NBUK];
    for (int b = threadIdx.x; b < NBUK; b += 256) lcnt[b] = 0;
    __syncthreads();
    const int q0 = blockIdx.x * (EPB / 4);
#pragma unroll
    for (int k = 0; k < EPB / 1024; ++k) {
        int q = q0 + k * 256 + threadIdx.x;
        if (q < NE / 4) {
            int4 r = rows4[q];
            atomicAdd(&lcnt[r.x >> BSHIFT], 1);
            atomicAdd(&lcnt[r.y >> BSHIFT], 1);
            atomicAdd(&lcnt[r.z >> BSHIFT], 1);
            atomicAdd(&lcnt[r.w >> BSHIFT], 1);
        }
    }
    __syncthreads();
    for (int b = threadIdx.x; b < NBUK; b += 256) {
        int c = lcnt[b];
        if (c) atomicAdd(&bcnt[b], c);
    }
}

__global__ __launch_bounds__(512) void bscan(const int* __restrict__ bcnt,
                                             int* __restrict__ bsc,
                                             int* __restrict__ gcur) {
    __shared__ int buf[512];
    int t = threadIdx.x;
    int v = (t < NBUK) ? bcnt[t] : 0;
    buf[t] = v;
    __syncthreads();
    for (int off = 1; off < 512; off <<= 1) {
        int x = (t >= off) ? buf[t - off] : 0;
        __syncthreads();
        buf[t] += x;
        __syncthreads();
    }
    if (t < NBUK) {
        int excl = buf[t] - v;
        bsc[t]  = excl;
        gcur[t] = excl;
    }
    if (t == NBUK - 1) bsc[NBUK] = buf[t];   // == NE
}

// partition: records packed {(lrow<<18)|col, val_bits}; each block reserves
// one contiguous run per bucket -> coalesced-ish writes, no hot atomics.
__global__ __launch_bounds__(256) void part_kernel(const int4* __restrict__ rows4,
                                                   const int4* __restrict__ cols4,
                                                   const float4* __restrict__ vals4,
                                                   int* __restrict__ gcur,
                                                   uint2* __restrict__ part) {
    __shared__ int lcnt[NBUK];
    __shared__ int lbase[NBUK];
    for (int b = threadIdx.x; b < NBUK; b += 256) lcnt[b] = 0;
    __syncthreads();
    const int q0 = blockIdx.x * (EPB / 4);
    int4 rc[EPB / 1024];
#pragma unroll
    for (int k = 0; k < EPB / 1024; ++k) {
        int q = q0 + k * 256 + threadIdx.x;
        if (q < NE / 4) {
            int4 r = rows4[q];
            rc[k] = r;
            atomicAdd(&lcnt[r.x >> BSHIFT], 1);
            atomicAdd(&lcnt[r.y >> BSHIFT], 1);
            atomicAdd(&lcnt[r.z >> BSHIFT], 1);
            atomicAdd(&lcnt[r.w >> BSHIFT], 1);
        } else {
            rc[k] = make_int4(-1, -1, -1, -1);
        }
    }
    __syncthreads();
    for (int b = threadIdx.x; b < NBUK; b += 256) {
        int c = lcnt[b];
        lbase[b] = c ? atomicAdd(&gcur[b], c) : 0;
        lcnt[b] = 0;                       // reset for rank assignment
    }
    __syncthreads();
#pragma unroll
    for (int k = 0; k < EPB / 1024; ++k) {
        int q = q0 + k * 256 + threadIdx.x;
        if (q < NE / 4) {
            int4   c4 = cols4[q];
            float4 v4 = vals4[q];
            int r, b, rk;
            uint2 rec;
            r = rc[k].x; b = r >> BSHIFT; rk = atomicAdd(&lcnt[b], 1);
            rec.x = ((u32)(r & (BROWS - 1)) << 18) | (u32)c4.x;
            rec.y = __float_as_uint(v4.x);  part[lbase[b] + rk] = rec;
            r = rc[k].y; b = r >> BSHIFT; rk = atomicAdd(&lcnt[b], 1);
            rec.x = ((u32)(r & (BROWS - 1)) << 18) | (u32)c4.y;
            rec.y = __float_as_uint(v4.y);  part[lbase[b] + rk] = rec;
            r = rc[k].z; b = r >> BSHIFT; rk = atomicAdd(&lcnt[b], 1);
            rec.x = ((u32)(r & (BROWS - 1)) << 18) | (u32)c4.z;
            rec.y = __float_as_uint(v4.z);  part[lbase[b] + rk] = rec;
            r = rc[k].w; b = r >> BSHIFT; rk = atomicAdd(&lcnt[b], 1);
            rec.x = ((u32)(r & (BROWS - 1)) << 18) | (u32)c4.w;
            rec.y = __float_as_uint(v4.w);  part[lbase[b] + rk] = rec;
        }
    }
}

// one block per bucket: row-hist -> LDS scan -> rs/deg, then LDS-cursor fill
__global__ __launch_bounds__(512) void bfill(const uint2* __restrict__ part,
                                             const int* __restrict__ bsc,
                                             int* __restrict__ rs,
                                             int* __restrict__ deg,
                                             uint2* __restrict__ ep) {
    __shared__ int h[BROWS];
    __shared__ int sc[BROWS];
    const int b = blockIdx.x;
    const int t = threadIdx.x;
    const int s = bsc[b];
    const int e = bsc[b + 1];
    h[t] = 0;
    __syncthreads();
    for (int i = s + t; i < e; i += 512)
        atomicAdd(&h[part[i].x >> 18], 1);
    __syncthreads();
    int v = h[t];
    sc[t] = v;
    __syncthreads();
    for (int off = 1; off < 512; off <<= 1) {
        int x = (t >= off) ? sc[t - off] : 0;
        __syncthreads();
        sc[t] += x;
        __syncthreads();
    }
    const int row = b * BROWS + t;
    if (row < N_NODES) {
        deg[row] = v;
        rs[row]  = s + sc[t];              // row_end convention
    }
    h[t] = s + sc[t] - v;                  // cursor = row_start
    __syncthreads();
    for (int i = s + t; i < e; i += 512) {
        uint2 rec = part[i];
        int lr  = rec.x >> 18;
        int pos = atomicAdd(&h[lr], 1);
        uint2 o;
        o.x = rec.x & 0x3FFFF;
        o.y = rec.y;
        ep[pos] = o;                       // bucket slice ~40 KB -> L2-local
    }
}

// ===========================================================================
// Fused layer (r10 = r9 structure, fp16 tables, no e1 round-trip).
// Gather: wave-per-row; records loaded SCALAR; pad slots masked to col=0;
// 8 table lines in flight (DIN=64); fma over fp16 halves folds to
// v_fma_mix_f32. NAMED SCALARS ONLY.
// EGO: 0 = ue/ee fp32 (L0), 2 = tin fp16 (L1, L2).
// mfma_f32_16x16x32_f16 (same shape/rate as bf16; layouts identical):
// A[row=l&15][k=(l>>4)*8+j], B[k][col=l&15], D col=l&15, row=(l>>4)*4+reg.
// ===========================================================================
template <int DIN, int DOUT, int EGO>
__global__ __launch_bounds__(256) void layer_fused(
        const int* __restrict__ rs, const int* __restrict__ deg,
        const uint2* __restrict__ ep,
        const unsigned short* __restrict__ tin,
        const float* __restrict__ ue, const float* __restrict__ ee,
        const unsigned short* __restrict__ WgT,   // fp16 [DOUT][DIN]
        const unsigned short* __restrict__ WbT,
        const float* __restrict__ bg, const float* __restrict__ bb,
        unsigned short* __restrict__ tout,        // fp16 [N][DOUT]
        float* __restrict__ norm_out) {
    constexpr int NTC = DOUT / 16;        // col tiles per block
    constexpr int R   = (4 / NTC) * 16;   // rows per block
    constexpr int RPW = R / 4;            // rows gathered per wave
    constexpr int KS  = DIN / 32;

    __shared__ __align__(16) unsigned short sH[R * DIN];
    __shared__ __align__(16) unsigned short sP[R * DIN];
    __shared__ float sPart[R * NTC];

    const int lane    = threadIdx.x & 63;
    const int wave    = threadIdx.x >> 6;
    const int rowbase = blockIdx.x * R;

    // ---- gather phase: wave gathers its RPW rows sequentially ----
    for (int rr = 0; rr < RPW; ++rr) {
        const int lr  = wave * RPW + rr;
        const int row = __builtin_amdgcn_readfirstlane(rowbase + lr);
        const int end   = rs[row];
        const int start = end - deg[row];

        if (DIN == 64) {
            const int g  = lane >> 5;          // half-wave: edge sub-slot
            const int d2 = lane & 31;          // fp16-pair index
            const u32* t32 = (const u32*)tin;
            float ax0 = 0.f, ax1 = 0.f, ax2 = 0.f, ax3 = 0.f;
            float ay0 = 0.f, ay1 = 0.f, ay2 = 0.f, ay3 = 0.f;
            for (int i = start; i < end; i += 16) {
                const int rem = end - i;               // uniform
                // 16 scalar record loads (uniform addrs -> s_load)
                uint2 q0  = ep[i + 0],  q1  = ep[i + 1];
                uint2 q2  = ep[i + 2],  q3  = ep[i + 3];
                uint2 q4  = ep[i + 4],  q5  = ep[i + 5];
                uint2 q6  = ep[i + 6],  q7  = ep[i + 7];
                uint2 q8  = ep[i + 8],  q9  = ep[i + 9];
                uint2 q10 = ep[i + 10], q11 = ep[i + 11];
                uint2 q12 = ep[i + 12], q13 = ep[i + 13];
                uint2 q14 = ep[i + 14], q15 = ep[i + 15];
                // uniform pad-masking (scalar cselect): pad -> col 0, val 0
                u32 m0  = (0  < rem) ? q0.x  : 0u;  u32 w0  = (0  < rem) ? q0.y  : 0u;
                u32 m1  = (1  < rem) ? q1.x  : 0u;  u32 w1  = (1  < rem) ? q1.y  : 0u;
                u32 m2  = (2  < rem) ? q2.x  : 0u;  u32 w2  = (2  < rem) ? q2.y  : 0u;
                u32 m3  = (3  < rem) ? q3.x  : 0u;  u32 w3  = (3  < rem) ? q3.y  : 0u;
                u32 m4  = (4  < rem) ? q4.x  : 0u;  u32 w4  = (4  < rem) ? q4.y  : 0u;
                u32 m5  = (5  < rem) ? q5.x  : 0u;  u32 w5  = (5  < rem) ? q5.y  : 0u;
                u32 m6  = (6  < rem) ? q6.x  : 0u;  u32 w6  = (6  < rem) ? q6.y  : 0u;
                u32 m7  = (7  < rem) ? q7.x  : 0u;  u32 w7  = (7  < rem) ? q7.y  : 0u;
                u32 m8  = (8  < rem) ? q8.x  : 0u;  u32 w8  = (8  < rem) ? q8.y  : 0u;
                u32 m9  = (9  < rem) ? q9.x  : 0u;  u32 w9  = (9  < rem) ? q9.y  : 0u;
                u32 m10 = (10 < rem) ? q10.x : 0u;  u32 w10 = (10 < rem) ? q10.y : 0u;
                u32 m11 = (11 < rem) ? q11.x : 0u;  u32 w11 = (11 < rem) ? q11.y : 0u;
                u32 m12 = (12 < rem) ? q12.x : 0u;  u32 w12 = (12 < rem) ? q12.y : 0u;
                u32 m13 = (13 < rem) ? q13.x : 0u;  u32 w13 = (13 < rem) ? q13.y : 0u;
                u32 m14 = (14 < rem) ? q14.x : 0u;  u32 w14 = (14 < rem) ? q14.y : 0u;
                u32 m15 = (15 < rem) ? q15.x : 0u;  u32 w15 = (15 < rem) ? q15.y : 0u;
                // half-wave slot selects (1 cndmask each)
                u32 s0 = g ? m1  : m0;   float v0 = __uint_as_float(g ? w1  : w0);
                u32 s1 = g ? m3  : m2;   float v1 = __uint_as_float(g ? w3  : w2);
                u32 s2 = g ? m5  : m4;   float v2 = __uint_as_float(g ? w5  : w4);
                u32 s3 = g ? m7  : m6;   float v3 = __uint_as_float(g ? w7  : w6);
                u32 s4 = g ? m9  : m8;   float v4 = __uint_as_float(g ? w9  : w8);
                u32 s5 = g ? m11 : m10;  float v5 = __uint_as_float(g ? w11 : w10);
                u32 s6 = g ? m13 : m12;  float v6 = __uint_as_float(g ? w13 : w12);
                u32 s7 = g ? m15 : m14;  float v7 = __uint_as_float(g ? w15 : w14);
                // 8 table lines in flight
                u32 x0 = t32[(size_t)s0 * 32 + d2];
                u32 x1 = t32[(size_t)s1 * 32 + d2];
                u32 x2 = t32[(size_t)s2 * 32 + d2];
                u32 x3 = t32[(size_t)s3 * 32 + d2];
                u32 x4 = t32[(size_t)s4 * 32 + d2];
                u32 x5 = t32[(size_t)s5 * 32 + d2];
                u32 x6 = t32[(size_t)s6 * 32 + d2];
                u32 x7 = t32[(size_t)s7 * 32 + d2];
                ax0 = fmaf(v0, hlo(x0), ax0);  ay0 = fmaf(v0, hhi(x0), ay0);
                ax1 = fmaf(v1, hlo(x1), ax1);  ay1 = fmaf(v1, hhi(x1), ay1);
                ax2 = fmaf(v2, hlo(x2), ax2);  ay2 = fmaf(v2, hhi(x2), ay2);
                ax3 = fmaf(v3, hlo(x3), ax3);  ay3 = fmaf(v3, hhi(x3), ay3);
                ax0 = fmaf(v4, hlo(x4), ax0);  ay0 = fmaf(v4, hhi(x4), ay0);
                ax1 = fmaf(v5, hlo(x5), ax1);  ay1 = fmaf(v5, hhi(x5), ay1);
                ax2 = fmaf(v6, hlo(x6), ax2);  ay2 = fmaf(v6, hhi(x6), ay2);
                ax3 = fmaf(v7, hlo(x7), ax3);  ay3 = fmaf(v7, hhi(x7), ay3);
            }
            float ax = (ax0 + ax1) + (ax2 + ax3);
            float ay = (ay0 + ay1) + (ay2 + ay3);
            ax += __shfl_xor(ax, 32);
            ay += __shfl_xor(ay, 32);

            float ex, ey;
            if (EGO == 0) {
                const float2* src = (row < N_USERS)
                    ? (const float2*)ue + (size_t)row * 32
                    : (const float2*)ee + (size_t)(row - N_USERS) * 32;
                float2 ev = src[d2];  ex = ev.x;  ey = ev.y;
            } else {
                u32 tv = t32[(size_t)row * 32 + d2];
                ex = hlo(tv);  ey = hhi(tv);
            }
            if (g == 0) {
                ((u32*)sH)[lr * 32 + d2] = pkh(ex + ax, ey + ay);
                ((u32*)sP)[lr * 32 + d2] = pkh(ex * ax, ey * ay);
            }
        } else {   // DIN == 32: quarter-waves, 16 edges/iter, 4 lines in flight
            const int g  = lane >> 4;          // 0..3
            const int d2 = lane & 15;
            const u32* t16 = (const u32*)tin;
            float ax0 = 0.f, ax1 = 0.f;
            float ay0 = 0.f, ay1 = 0.f;
            for (int i = start; i < end; i += 16) {
                const int rem = end - i;
                uint2 q0  = ep[i + 0],  q1  = ep[i + 1];
                uint2 q2  = ep[i + 2],  q3  = ep[i + 3];
                uint2 q4  = ep[i + 4],  q5  = ep[i + 5];
                uint2 q6  = ep[i + 6],  q7  = ep[i + 7];
                uint2 q8  = ep[i + 8],  q9  = ep[i + 9];
                uint2 q10 = ep[i + 10], q11 = ep[i + 11];
                uint2 q12 = ep[i + 12], q13 = ep[i + 13];
                uint2 q14 = ep[i + 14], q15 = ep[i + 15];
                u32 m0  = (0  < rem) ? q0.x  : 0u;  u32 w0  = (0  < rem) ? q0.y  : 0u;
                u32 m1  = (1  < rem) ? q1.x  : 0u;  u32 w1  = (1  < rem) ? q1.y  : 0u;
                u32 m2  = (2  < rem) ? q2.x  : 0u;  u32 w2  = (2  < rem) ? q2.y  : 0u;
                u32 m3  = (3  < rem) ? q3.x  : 0u;  u32 w3  = (3  < rem) ? q3.y  : 0u;
                u32 m4  = (4  < rem) ? q4.x  : 0u;  u32 w4  = (4  < rem) ? q4.y  : 0u;
                u32 m5  = (5  < rem) ? q5.x  : 0u;  u32 w5  = (5  < rem) ? q5.y  : 0u;
                u32 m6  = (6  < rem) ? q6.x  : 0u;  u32 w6  = (6  < rem) ? q6.y  : 0u;
                u32 m7  = (7  < rem) ? q7.x  : 0u;  u32 w7  = (7  < rem) ? q7.y  : 0u;
                u32 m8  = (8  < rem) ? q8.x  : 0u;  u32 w8  = (8  < rem) ? q8.y  : 0u;
                u32 m9  = (9  < rem) ? q9.x  : 0u;  u32 w9  = (9  < rem) ? q9.y  : 0u;
                u32 m10 = (10 < rem) ? q10.x : 0u;  u32 w10 = (10 < rem) ? q10.y : 0u;
                u32 m11 = (11 < rem) ? q11.x : 0u;  u32 w11 = (11 < rem) ? q11.y : 0u;
                u32 m12 = (12 < rem) ? q12.x : 0u;  u32 w12 = (12 < rem) ? q12.y : 0u;
                u32 m13 = (13 < rem) ? q13.x : 0u;  u32 w13 = (13 < rem) ? q13.y : 0u;
                u32 m14 = (14 < rem) ? q14.x : 0u;  u32 w14 = (14 < rem) ? q14.y : 0u;
                u32 m15 = (15 < rem) ? q15.x : 0u;  u32 w15 = (15 < rem) ? q15.y : 0u;
                // quarter-wave slot selects: slot k covers edges 4k+g
                u32 ta, tb; float fa, fb;
                ta = (g & 1) ? m1  : m0;   tb = (g & 1) ? m3  : m2;
                fa = __uint_as_float((g & 1) ? w1  : w0);
                fb = __uint_as_float((g & 1) ? w3  : w2);
                u32 s0 = (g & 2) ? tb : ta;  float v0 = (g & 2) ? fb : fa;
                ta = (g & 1) ? m5  : m4;   tb = (g & 1) ? m7  : m6;
                fa = __uint_as_float((g & 1) ? w5  : w4);
                fb = __uint_as_float((g & 1) ? w7  : w6);
                u32 s1 = (g & 2) ? tb : ta;  float v1 = (g & 2) ? fb : fa;
                ta = (g & 1) ? m9  : m8;   tb = (g & 1) ? m11 : m10;
                fa = __uint_as_float((g & 1) ? w9  : w8);
                fb = __uint_as_float((g & 1) ? w11 : w10);
                u32 s2 = (g & 2) ? tb : ta;  float v2 = (g & 2) ? fb : fa;
                ta = (g & 1) ? m13 : m12;  tb = (g & 1) ? m15 : m14;
                fa = __uint_as_float((g & 1) ? w13 : w12);
                fb = __uint_as_float((g & 1) ? w15 : w14);
                u32 s3 = (g & 2) ? tb : ta;  float v3 = (g & 2) ? fb : fa;
                u32 x0 = t16[(size_t)s0 * 16 + d2];
                u32 x1 = t16[(size_t)s1 * 16 + d2];
                u32 x2 = t16[(size_t)s2 * 16 + d2];
                u32 x3 = t16[(size_t)s3 * 16 + d2];
                ax0 = fmaf(v0, hlo(x0), ax0);  ay0 = fmaf(v0, hhi(x0), ay0);
                ax1 = fmaf(v1, hlo(x1), ax1);  ay1 = fmaf(v1, hhi(x1), ay1);
                ax0 = fmaf(v2, hlo(x2), ax0);  ay0 = fmaf(v2, hhi(x2), ay0);
                ax1 = fmaf(v3, hlo(x3), ax1);  ay1 = fmaf(v3, hhi(x3), ay1);
            }
            float ax = ax0 + ax1;
            float ay = ay0 + ay1;
            ax += __shfl_xor(ax, 32);  ay += __shfl_xor(ay, 32);
            ax += __shfl_xor(ax, 16);  ay += __shfl_xor(ay, 16);

            float ex, ey;
            if (EGO == 0) {
                const float2* src = (row < N_USERS)
                    ? (const float2*)ue + (size_t)row * 32
                    : (const float2*)ee + (size_t)(row - N_USERS) * 32;
                float2 ev = src[d2];  ex = ev.x;  ey = ev.y;
            } else {
                u32 tv = t16[(size_t)row * 16 + d2];
                ex = hlo(tv);  ey = hhi(tv);
            }
            if (g == 0) {
                ((u32*)sH)[lr * 16 + d2] = pkh(ex + ax, ey + ay);
                ((u32*)sP)[lr * 16 + d2] = pkh(ex * ax, ey * ay);
            }
        }
    }
    __syncthreads();

    // ---- MFMA phase: wave (rt, ct) computes 16 rows x 16 cols ----
    const int ct  = wave % NTC;
    const int rt  = wave / NTC;
    const int r16 = lane & 15;
    const int g4  = lane >> 4;

    f16x8 ah[KS], ap[KS];
#pragma unroll
    for (int s = 0; s < KS; ++s) {
        const int aoff = (rt * 16 + r16) * DIN + g4 * 8 + s * 32;
        ah[s] = *reinterpret_cast<const f16x8*>(sH + aoff);
        ap[s] = *reinterpret_cast<const f16x8*>(sP + aoff);
    }
    f32x4 accg = (f32x4){0.f, 0.f, 0.f, 0.f};
    f32x4 accb = (f32x4){0.f, 0.f, 0.f, 0.f};
#pragma unroll
    for (int s = 0; s < KS; ++s) {
        const int boff = (ct * 16 + r16) * DIN + g4 * 8 + s * 32;
        f16x8 bgf = *reinterpret_cast<const f16x8*>(WgT + boff);
        f16x8 bbf = *reinterpret_cast<const f16x8*>(WbT + boff);
        accg = __builtin_amdgcn_mfma_f32_16x16x32_f16(ah[s], bgf, accg, 0, 0, 0);
        accb = __builtin_amdgcn_mfma_f32_16x16x32_f16(ap[s], bbf, accb, 0, 0, 0);
    }

    // epilogue: bias + leaky + sum, stores, per-row norm partials
    const int col = ct * 16 + r16;
    const float bgv = bg[col];
    const float bbv = bb[col];
    float ss[4];
#pragma unroll
    for (int r = 0; r < 4; ++r) {
        float a = accg[r] + bgv; a = a > 0.f ? a : 0.01f * a;
        float b = accb[r] + bbv; b = b > 0.f ? b : 0.01f * b;
        float nv = a + b;
        const int row = rowbase + rt * 16 + g4 * 4 + r;
        tout[(size_t)row * DOUT + col] = f2h(nv);
        ss[r] = nv * nv;
    }
#pragma unroll
    for (int off = 1; off < 16; off <<= 1) {
#pragma unroll
        for (int r = 0; r < 4; ++r) ss[r] += __shfl_xor(ss[r], off);
    }
    if (r16 == 0) {
#pragma unroll
        for (int r = 0; r < 4; ++r)
            sPart[(rt * 16 + g4 * 4 + r) * NTC + ct] = ss[r];
    }
    __syncthreads();
    for (int t = threadIdx.x; t < R; t += 256) {
        float s = 0.f;
#pragma unroll
        for (int j = 0; j < NTC; ++j) s += sPart[t * NTC + j];
        norm_out[rowbase + t] = fmaxf(sqrtf(s), 1e-12f);
    }
}

// ===========================================================================
// Scoring: one wave per batch element; sections 64 raw (fp32 inputs) +
// 64 (t1 fp16) + 32 (t2 fp16) + 16 (t3 fp16); norms folded as reciprocals.
// ===========================================================================
__global__ __launch_bounds__(256) void score_kernel(
        const int* __restrict__ users, const int* __restrict__ pos,
        const int* __restrict__ neg,
        const float* __restrict__ ue, const float* __restrict__ ee,
        const unsigned short* __restrict__ t1, const float* __restrict__ n0,
        const unsigned short* __restrict__ t2, const float* __restrict__ n1,
        const unsigned short* __restrict__ t3, const float* __restrict__ n2,
        float* __restrict__ out) {
    int gid  = blockIdx.x * 256 + threadIdx.x;
    int idx  = gid >> 6;
    int lane = gid & 63;
    if (idx >= BATCH) return;
    int u  = users[idx];
    int pe = pos[idx];
    int ne = neg[idx];
    int pn = N_USERS + pe;
    int nn = N_USERS + ne;

    float s1p = 1.0f / (n0[u] * n0[pn]);
    float s1n = 1.0f / (n0[u] * n0[nn]);
    float s2p = 1.0f / (n1[u] * n1[pn]);
    float s2n = 1.0f / (n1[u] * n1[nn]);
    float s3p = 1.0f / (n2[u] * n2[pn]);
    float s3n = 1.0f / (n2[u] * n2[nn]);

    float ap = 0.f, an = 0.f;
    {
        float xu = ue[(size_t)u * 64 + lane];
        ap += xu * ee[(size_t)pe * 64 + lane];
        an += xu * ee[(size_t)ne * 64 + lane];
    }
    {
        float xu = h2f(t1[(size_t)u * 64 + lane]);
        ap += xu * h2f(t1[(size_t)pn * 64 + lane]) * s1p;
        an += xu * h2f(t1[(size_t)nn * 64 + lane]) * s1n;
    }
    if (lane < 32) {
        float xu = h2f(t2[(size_t)u * 32 + lane]);
        ap += xu * h2f(t2[(size_t)pn * 32 + lane]) * s2p;
        an += xu * h2f(t2[(size_t)nn * 32 + lane]) * s2n;
    } else if (lane < 48) {
        int d = lane - 32;
        float xu = h2f(t3[(size_t)u * 16 + d]);
        ap += xu * h2f(t3[(size_t)pn * 16 + d]) * s3p;
        an += xu * h2f(t3[(size_t)nn * 16 + d]) * s3n;
    }
#pragma unroll
    for (int off = 32; off > 0; off >>= 1) {
        ap += __shfl_xor(ap, off);
        an += __shfl_xor(an, off);
    }
    if (lane == 0) {
        out[2 * idx + 0] = ap;
        out[2 * idx + 1] = an;
    }
}

// ===========================================================================
extern "C" void kernel_launch(void* const* d_in, const int* in_sizes, int n_in,
                              void* d_out, int out_size, void* d_ws, size_t ws_size,
                              hipStream_t stream) {
    const int*   users = (const int*)d_in[0];
    const int*   pos   = (const int*)d_in[1];
    const int*   neg   = (const int*)d_in[2];
    const int*   rows  = (const int*)d_in[3];
    const int*   cols  = (const int*)d_in[4];
    const float* vals  = (const float*)d_in[5];
    const float* ue    = (const float*)d_in[6];
    const float* ee    = (const float*)d_in[7];
    const float* Wg0 = (const float*)d_in[8],  *bg0 = (const float*)d_in[9];
    const float* Wb0 = (const float*)d_in[10], *bb0 = (const float*)d_in[11];
    const float* Wg1 = (const float*)d_in[12], *bg1 = (const float*)d_in[13];
    const float* Wb1 = (const float*)d_in[14], *bb1 = (const float*)d_in[15];
    const float* Wg2 = (const float*)d_in[16], *bg2 = (const float*)d_in[17];
    const float* Wb2 = (const float*)d_in[18], *bb2 = (const float*)d_in[19];

    // workspace (~93 MB; >=192 MB proven available). e1 fp32 ELIMINATED
    // (r10): scoring section 2 and L1 ego read tB fp16 instead.
    float* n0   = (float*)d_ws;                          // N
    float* n1   = n0 + N_NODES;                          // N
    float* n2   = n1 + N_NODES;                          // N
    uint2* ep   = (uint2*)(n2 + N_NODES);                // E packed {col, val}
    unsigned short* tA = (unsigned short*)(ep + NE);     // N x 64 fp16 (t0, then t2)
    unsigned short* tB = tA + (size_t)N_NODES * 64;      // N x 64 fp16 (t1)
    unsigned short* t3 = tB + (size_t)N_NODES * 64;      // N x 16 fp16 (L3 out)
    unsigned short* wt = t3 + (size_t)N_NODES * 16;      // 13312 (transposed weights)
    int* deg  = (int*)(wt + 13312);                      // N
    int* rs   = deg + N_NODES;                           // N
    int* bcnt = rs + N_NODES;                            // NBUK
    int* bsc  = bcnt + NBUK;                             // NBUK + 1
    int* gcur = bsc + NBUK + 1;                          // NBUK
    uint2* part = (uint2*)(gcur + NBUK);                 // E records (16 MB)

    // ---- CSR build via bucket sort; init (t0 + weights) fused into bhist ----
    hipMemsetAsync(bcnt, 0, NBUK * sizeof(int), stream);
    bhist<<<PBLK + T0_BLKS + WT_BLKS, 256, 0, stream>>>(
        (const int4*)rows, bcnt, ue, ee, tA,
        Wg0, Wb0, Wg1, Wb1, Wg2, Wb2, wt);
    bscan<<<1, 512, 0, stream>>>(bcnt, bsc, gcur);
    part_kernel<<<PBLK, 256, 0, stream>>>((const int4*)rows, (const int4*)cols,
                                          (const float4*)vals, gcur, part);
    bfill<<<NBUK, 512, 0, stream>>>(part, bsc, rs, deg, ep);

    // ---- 3 fused layers: gather -> LDS -> MFMA -> stores + norm ----
    layer_fused<64, 64, 0><<<N_NODES / 16, 256, 0, stream>>>(
        rs, deg, ep, tA, ue, ee, wt, wt + 4096, bg0, bb0, tB, n0);
    layer_fused<64, 32, 2><<<N_NODES / 32, 256, 0, stream>>>(
        rs, deg, ep, tB, ue, ee, wt + 8192, wt + 10240, bg1, bb1, tA, n1);
    layer_fused<32, 16, 2><<<N_NODES / 64, 256, 0, stream>>>(
        rs, deg, ep, tA, ue, ee, wt + 12288, wt + 12800, bg2, bb2, t3, n2);

    // ---- scoring ----
    score_kernel<<<(BATCH * 64) / 256, 256, 0, stream>>>(users, pos, neg, ue, ee,
                                                         tB, n0, tA, n1, t3, n2,
                                                         (float*)d_out);
}